// Round 8
// baseline (308.351 us; speedup 1.0000x reference)
//
#include <hip/hip_runtime.h>
#include <hip/hip_bf16.h>

typedef _Float16 f16;
typedef _Float16 f16x2 __attribute__((ext_vector_type(2)));
typedef _Float16 f16x4 __attribute__((ext_vector_type(4)));
typedef _Float16 f16x8 __attribute__((ext_vector_type(8)));
typedef float f32x4 __attribute__((ext_vector_type(4)));

// cvt_pkrtz returns __fp16 ext_vector(2); re-cast to our f16x2 (same bits).
__device__ __forceinline__ f16x2 pkrtz(float a, float b) {
    auto r = __builtin_amdgcn_cvt_pkrtz(a, b);
    f16x2 o; o[0] = (f16)r[0]; o[1] = (f16)r[1];
    return o;
}

#define XT_ROWS 1027
#define XT_BSTRIDE (XT_ROWS * 1024)   // elems per batch

// ---------------------------------------------------------------------------
// global -> LDS direct (16B per lane, wave-uniform LDS base + lane*16)
// ---------------------------------------------------------------------------
__device__ __forceinline__ void gload16(const f16* g, f16* l) {
    __builtin_amdgcn_global_load_lds(
        (const __attribute__((address_space(1))) void*)g,
        (__attribute__((address_space(3))) void*)l, 16, 0, 0);
}

// ---------------------------------------------------------------------------
// Stage a 128x64 f16 tile from row-major src (ld elems) into 16KB LDS.
// XOR-swizzle: LDS slot (row, cs) holds tile(row, (cs^(row&7))*8 .. +8).
// Linear LDS dest (gload_lds requirement); swizzle applied on the SOURCE col
// and identically on the read side (involution) -> conflict-free ds_read_b128.
// ---------------------------------------------------------------------------
__device__ __forceinline__ void stage_tile(const f16* src, int ld, f16* lds)
{
    const int tid = threadIdx.x;
    const int w512 = (tid >> 6) << 9;          // wave base (f16 elems)
    #pragma unroll
    for (int q = 0; q < 4; ++q) {
        const int s = q * 256 + tid;           // 16B slot id, 0..1023
        const int row = s >> 3;
        const int col = ((s & 7) ^ (row & 7)) << 3;
        gload16(src + row * ld + col, lds + (q << 11) + w512);
    }
}

// ---------------------------------------------------------------------------
// GEMM core (m97 structure): C(128x128) += A(128xK) * Bt(128xK)^T.
// BK=64, global_load_lds staging, swizzled LDS, 2 barriers per k-step.
// CONV=1: A row base = m0 + (k0>>10) into zero-padded Xt (no bounds checks),
//         A col = k0&1023.
// 256 threads = 4 waves (2x2), each wave 64x64 = 4x4 frags of 16x16x32.
// ---------------------------------------------------------------------------
template <int CONV>
__device__ __forceinline__ void gemm_core64(
    const f16* __restrict__ A, int lda, int m0,
    const f16* __restrict__ Bt, int ldb, int K,
    f16* Alds, f16* Blds, f32x4 acc[4][4])
{
    const int tid = threadIdx.x;
    const int lid = tid & 63;
    const int wv  = tid >> 6;
    const int wm  = (wv >> 1) * 64;
    const int wn  = (wv & 1) * 64;
    const int g   = lid >> 4;
    const int r15 = lid & 15;

    for (int k0 = 0; k0 < K; k0 += 64) {
        const f16* Asrc;
        if (CONV) {
            const int f = k0 >> 10;
            Asrc = A + (m0 + f) * lda + (k0 & 1023);
        } else {
            Asrc = A + m0 * lda + k0;
        }
        __syncthreads();                 // previous iter's reads complete
        stage_tile(Asrc, lda, Alds);
        stage_tile(Bt + k0, ldb, Blds);
        __syncthreads();                 // vmcnt(0) drain + barrier
        #pragma unroll
        for (int kc = 0; kc < 2; ++kc) {
            f16x8 af[4], bf[4];
            #pragma unroll
            for (int mi = 0; mi < 4; ++mi) {
                const int row = wm + mi * 16 + r15;
                af[mi] = *(const f16x8*)(Alds + row * 64 +
                                         (((kc * 4 + g) ^ (row & 7)) << 3));
            }
            #pragma unroll
            for (int nj = 0; nj < 4; ++nj) {
                const int row = wn + nj * 16 + r15;
                bf[nj] = *(const f16x8*)(Blds + row * 64 +
                                         (((kc * 4 + g) ^ (row & 7)) << 3));
            }
            #pragma unroll
            for (int mi = 0; mi < 4; ++mi)
                #pragma unroll
                for (int nj = 0; nj < 4; ++nj)
                    acc[mi][nj] = __builtin_amdgcn_mfma_f32_16x16x32_f16(
                        af[mi], bf[nj], acc[mi][nj], 0, 0, 0);
        }
    }
}

// ---------------------------------------------------------------------------
// fp32 -> fp16 elementwise convert (float4 -> f16x4)
// ---------------------------------------------------------------------------
__global__ __launch_bounds__(256) void k_cvt(const float* __restrict__ in,
                                             f16* __restrict__ out, int n4)
{
    int i = blockIdx.x * 256 + threadIdx.x;
    if (i < n4) {
        float4 v = ((const float4*)in)[i];
        f16x4 o;
        o[0] = (f16)v.x; o[1] = (f16)v.y; o[2] = (f16)v.z; o[3] = (f16)v.w;
        ((f16x4*)out)[i] = o;
    }
}

// ---------------------------------------------------------------------------
// Transpose + convert: in (R x C) f32 -> out (C x R) f16.  R,C multiples of 32.
// ---------------------------------------------------------------------------
__global__ __launch_bounds__(256) void k_transpose_cvt(const float* __restrict__ in,
                                                       f16* __restrict__ out,
                                                       int R, int C)
{
    __shared__ float tile[32][33];
    int c0 = blockIdx.x * 32, r0 = blockIdx.y * 32;
    int tx = threadIdx.x, ty = threadIdx.y;
    #pragma unroll
    for (int i = ty; i < 32; i += 8)
        tile[i][tx] = in[(size_t)(r0 + i) * C + c0 + tx];
    __syncthreads();
    #pragma unroll
    for (int i = ty; i < 32; i += 8)
        out[(size_t)(c0 + i) * R + r0 + tx] = (f16)tile[tx][i];
}

// ---------------------------------------------------------------------------
// Transpose + zero-pad for the conv A-operand.
// in : per-batch (1024 c x 1024 t) f16; out: per-batch (1027 t' x 1024 c),
// out[t'][c] = in[c][t'-2] (rows t'<2 and t'>=1026 zero).
// grid (32, 33, 8): z = tensor*4 + batch.
// ---------------------------------------------------------------------------
__global__ __launch_bounds__(256) void k_transpose_pad(
    const f16* __restrict__ qx4, const f16* __restrict__ kx4,
    f16* __restrict__ XtQ, f16* __restrict__ XtK)
{
    int z = blockIdx.z, b = z & 3, ten = z >> 2;
    const f16* in = (ten ? kx4 : qx4) + (size_t)b * 1048576;
    f16* out = (ten ? XtK : XtQ) + (size_t)b * XT_BSTRIDE;
    __shared__ f16 tile[32][33];
    int c0 = blockIdx.x * 32;
    int tp0 = blockIdx.y * 32;
    int tx = threadIdx.x, ty = threadIdx.y;
    #pragma unroll
    for (int i = ty; i < 32; i += 8) {
        int t = tp0 + tx - 2;
        tile[i][tx] = (t >= 0 && t < 1024) ? in[(c0 + i) * 1024 + t] : (f16)0.f;
    }
    __syncthreads();
    #pragma unroll
    for (int i = ty; i < 32; i += 8) {
        int tp = tp0 + i;
        if (tp < XT_ROWS) out[tp * 1024 + c0 + tx] = tile[tx][i];
    }
}

// ---------------------------------------------------------------------------
// Projection GEMMs: z=0: q -> qx4 ; z=1: k -> kx4 ; z=2: v -> vT
// qx4/kx4: [b][h][l][d] ; vT: [b][h][d][l]
// ---------------------------------------------------------------------------
__global__ __launch_bounds__(256) void k_gemm_proj(
    const f16* __restrict__ Qh, const f16* __restrict__ Kh, const f16* __restrict__ Vh,
    const f16* __restrict__ WQt, const f16* __restrict__ WKt, const f16* __restrict__ WVt,
    const float* __restrict__ bQ, const float* __restrict__ bK, const float* __restrict__ bV,
    f16* __restrict__ qx4, f16* __restrict__ kx4, f16* __restrict__ vT)
{
    __shared__ __align__(16) f16 Alds[128 * 64];
    __shared__ __align__(16) f16 Blds[128 * 64];
    const int z = blockIdx.z;
    const f16* A  = z == 0 ? Qh : z == 1 ? Kh : Vh;
    const f16* Bt = z == 0 ? WQt : z == 1 ? WKt : WVt;
    const float* bias = z == 0 ? bQ : z == 1 ? bK : bV;
    f16* dst = z == 0 ? qx4 : z == 1 ? kx4 : vT;
    const int m0 = blockIdx.y * 128, n0 = blockIdx.x * 128;
    f32x4 acc[4][4] = {};
    gemm_core64<0>(A, 1024, m0, Bt + n0 * 1024, 1024, 1024, Alds, Blds, acc);

    const int tid = threadIdx.x, lid = tid & 63, wv = tid >> 6;
    const int wm = (wv >> 1) * 64, wn = (wv & 1) * 64, g = lid >> 4, r15 = lid & 15;
    #pragma unroll
    for (int nj = 0; nj < 4; ++nj) {
        const int col = n0 + wn + nj * 16 + r15;
        const float bv = bias[col];
        const int h = col >> 6, d = col & 63;
        #pragma unroll
        for (int mi = 0; mi < 4; ++mi)
            #pragma unroll
            for (int j = 0; j < 4; ++j) {
                const int row = m0 + wm + mi * 16 + g * 4 + j;
                const int b = row >> 10, l = row & 1023;
                const float v = acc[mi][nj][j] + bv;
                const int off = b * 1048576 + h * 65536 +
                                (z == 2 ? (d * 1024 + l) : (l * 64 + d));
                dst[off] = (f16)v;
            }
    }
}

// ---------------------------------------------------------------------------
// Fused conv GEMM (both tensors): Out[t][o] = sum_{f<flen,c} Xt[t+f][c] *
// CT[o][f*1024+c], then += residual IN PLACE.  grid (8, 8, 8): z = ten*4+b.
// ---------------------------------------------------------------------------
__global__ __launch_bounds__(256) void k_gemm_conv(
    const f16* __restrict__ XtQ, const f16* __restrict__ XtK,
    const f16* __restrict__ CTq, const f16* __restrict__ CTk,
    f16* __restrict__ qx4, f16* __restrict__ kx4,
    const float* __restrict__ wvec)
{
    __shared__ __align__(16) f16 Alds[128 * 64];
    __shared__ __align__(16) f16 Blds[128 * 64];
    const int z = blockIdx.z, b = z & 3, ten = z >> 2;
    const f16* Xt = (ten ? XtK : XtQ) + (size_t)b * XT_BSTRIDE;
    const f16* CT = ten ? CTk : CTq;
    f16* dst = (ten ? kx4 : qx4) + (size_t)b * 1048576;

    // flen = FILTER_LENGTHS[argmax([2,4]*w)] ; argmax ties -> first index
    const int flen = (2.f * wvec[0] >= 4.f * wvec[1]) ? 2 : 4;
    const int K = flen << 10;

    const int m0 = blockIdx.y * 128, n0 = blockIdx.x * 128;
    f32x4 acc[4][4] = {};
    gemm_core64<1>(Xt, 1024, m0, CT + n0 * 4096, 4096, K, Alds, Blds, acc);

    const int tid = threadIdx.x, lid = tid & 63, wv = tid >> 6;
    const int wm = (wv >> 1) * 64, wn = (wv & 1) * 64, g = lid >> 4, r15 = lid & 15;
    #pragma unroll
    for (int nj = 0; nj < 4; ++nj) {
        const int col = n0 + wn + nj * 16 + r15;
        #pragma unroll
        for (int mi = 0; mi < 4; ++mi)
            #pragma unroll
            for (int j = 0; j < 4; ++j) {
                const int row = m0 + wm + mi * 16 + g * 4 + j;
                const int i = row * 1024 + col;
                dst[i] = (f16)(acc[mi][nj][j] + (float)dst[i]);
            }
    }
}

// ---------------------------------------------------------------------------
// Flash attention, shuffle-free inner loop + double-buffered K/V prefetch.
// grid (64 bh, 8 qt) -> all blocks sharing a head's K/V land on one XCD
// (linear id mod 8 == bh mod 8).  4 independent waves x 32 q-rows.
// Swapped QK^T; constant-shift exp; deferred row-sum; sigma' k-slot bijection
// on both PV operands (see round-5 notes).
// ---------------------------------------------------------------------------
struct KVfrag {
    f16x8 kf[4][2];
    f16x8 va[4][2];
};

__device__ __forceinline__ void load_kv(const f16* Kp, const f16* Vp,
                                        int kv0, int g, int r15, KVfrag& o)
{
    #pragma unroll
    for (int nj = 0; nj < 4; ++nj)
        #pragma unroll
        for (int kc = 0; kc < 2; ++kc)
            o.kf[nj][kc] = *(const f16x8*)(Kp + (kv0 + nj * 16 + r15) * 64 + kc * 32 + g * 8);
    #pragma unroll
    for (int db = 0; db < 4; ++db)
        #pragma unroll
        for (int ch = 0; ch < 2; ++ch) {
            const f16* vp = Vp + (db * 16 + r15) * 1024 + kv0 + ch * 32 + g * 4;
            f16x4 lo = *(const f16x4*)vp;
            f16x4 hi = *(const f16x4*)(vp + 16);
            f16x8 v8;
            v8[0] = lo[0]; v8[1] = lo[1]; v8[2] = lo[2]; v8[3] = lo[3];
            v8[4] = hi[0]; v8[5] = hi[1]; v8[6] = hi[2]; v8[7] = hi[3];
            o.va[db][ch] = v8;
        }
}

__device__ __forceinline__ void compute_tile(const KVfrag& kv, const f16x8 qf[2][2],
                                             f32x4 o[2][4], f32x4 lsum[2])
{
    f32x4 sacc[2][4] = {};
    #pragma unroll
    for (int nj = 0; nj < 4; ++nj)
        #pragma unroll
        for (int kc = 0; kc < 2; ++kc) {
            sacc[0][nj] = __builtin_amdgcn_mfma_f32_16x16x32_f16(
                kv.kf[nj][kc], qf[0][kc], sacc[0][nj], 0, 0, 0);
            sacc[1][nj] = __builtin_amdgcn_mfma_f32_16x16x32_f16(
                kv.kf[nj][kc], qf[1][kc], sacc[1][nj], 0, 0, 0);
        }
    #pragma unroll
    for (int qh = 0; qh < 2; ++qh) {
        f32x4 pe[4];
        #pragma unroll
        for (int nj = 0; nj < 4; ++nj) {
            #pragma unroll
            for (int j = 0; j < 4; ++j)
                pe[nj][j] = __expf(sacc[qh][nj][j] - 2.0f);
            lsum[qh] += pe[nj];
        }
        f16x8 pb[2];
        #pragma unroll
        for (int ch = 0; ch < 2; ++ch) {
            union { f16x2 h2[4]; f16x8 v8; } u;
            u.h2[0] = pkrtz(pe[2 * ch][0], pe[2 * ch][1]);
            u.h2[1] = pkrtz(pe[2 * ch][2], pe[2 * ch][3]);
            u.h2[2] = pkrtz(pe[2 * ch + 1][0], pe[2 * ch + 1][1]);
            u.h2[3] = pkrtz(pe[2 * ch + 1][2], pe[2 * ch + 1][3]);
            pb[ch] = u.v8;
        }
        #pragma unroll
        for (int db = 0; db < 4; ++db)
            #pragma unroll
            for (int ch = 0; ch < 2; ++ch)
                o[qh][db] = __builtin_amdgcn_mfma_f32_16x16x32_f16(
                    kv.va[db][ch], pb[ch], o[qh][db], 0, 0, 0);
    }
}

__global__ __launch_bounds__(256) void k_attn(
    const f16* __restrict__ qn, const f16* __restrict__ kn,
    const f16* __restrict__ vT, f16* __restrict__ ctx)
{
    const int bh = blockIdx.x, b = bh >> 4, h = bh & 15;
    const f16* Qp = qn + (size_t)b * 1048576 + h * 65536;
    const f16* Kp = kn + (size_t)b * 1048576 + h * 65536;
    const f16* Vp = vT + (size_t)b * 1048576 + h * 65536;
    const int tid = threadIdx.x, lid = tid & 63, wv = tid >> 6;
    const int g = lid >> 4, r15 = lid & 15;
    const int q0 = blockIdx.y * 128 + wv * 32;

    __shared__ __align__(16) f16 Olds[4][32][72];

    // Q B-fragments (2 q-halves x 2 d-chunks), pre-scaled by 1/8 (exact)
    f16x8 qf[2][2];
    #pragma unroll
    for (int qh = 0; qh < 2; ++qh)
        #pragma unroll
        for (int kc = 0; kc < 2; ++kc) {
            f16x8 t = *(const f16x8*)(Qp + (q0 + qh * 16 + r15) * 64 + kc * 32 + g * 8);
            #pragma unroll
            for (int e = 0; e < 8; ++e) t[e] = t[e] * (f16)0.125f;
            qf[qh][kc] = t;
        }

    f32x4 o[2][4] = {};     // O[q=qh*16+r15][d=db*16+g*4+j]
    f32x4 lsum[2] = {};     // per-lane partial row sums

    KVfrag bufA, bufB;
    load_kv(Kp, Vp, 0, g, r15, bufA);
    #pragma unroll
    for (int tt = 0; tt < 8; ++tt) {
        load_kv(Kp, Vp, (2 * tt + 1) * 64, g, r15, bufB);
        compute_tile(bufA, qf, o, lsum);
        if (tt < 7)
            load_kv(Kp, Vp, (2 * tt + 2) * 64, g, r15, bufA);
        compute_tile(bufB, qf, o, lsum);
    }

    // Finalize row sums: in-lane horizontal + reduce over g-groups (xor 16,32)
    float inv[2];
    #pragma unroll
    for (int qh = 0; qh < 2; ++qh) {
        float lr = lsum[qh][0] + lsum[qh][1] + lsum[qh][2] + lsum[qh][3];
        lr += __shfl_xor(lr, 16);
        lr += __shfl_xor(lr, 32);
        inv[qh] = 1.0f / lr;
    }
    // Normalize, transpose via per-wave LDS slice, coalesced store.
    #pragma unroll
    for (int qh = 0; qh < 2; ++qh)
        #pragma unroll
        for (int db = 0; db < 4; ++db) {
            const int row = qh * 16 + r15, col = db * 16 + g * 4;
            *(f16x2*)&Olds[wv][row][col] =
                pkrtz(o[qh][db][0] * inv[qh], o[qh][db][1] * inv[qh]);
            *(f16x2*)&Olds[wv][row][col + 2] =
                pkrtz(o[qh][db][2] * inv[qh], o[qh][db][3] * inv[qh]);
        }
    asm volatile("s_waitcnt lgkmcnt(0)" ::: "memory");
    __builtin_amdgcn_sched_barrier(0);
    #pragma unroll
    for (int p = 0; p < 4; ++p) {
        const int row = p * 8 + (lid >> 3);
        const int c8 = (lid & 7) * 8;
        f16x8 v = *(const f16x8*)&Olds[wv][row][c8];
        *(f16x8*)(ctx + (size_t)b * 1048576 + (q0 + row) * 1024 + h * 64 + c8) = v;
    }
}

// ---------------------------------------------------------------------------
// Final GEMM: out = ctx @ Wfc + bfc, output FLOAT32 (B,L,1024) row-major.
// ---------------------------------------------------------------------------
__global__ __launch_bounds__(256) void k_gemm_final(
    const f16* __restrict__ ctx, const f16* __restrict__ WFt,
    const float* __restrict__ bfc, float* __restrict__ out)
{
    __shared__ __align__(16) f16 Alds[128 * 64];
    __shared__ __align__(16) f16 Blds[128 * 64];
    const int m0 = blockIdx.y * 128, n0 = blockIdx.x * 128;
    f32x4 acc[4][4] = {};
    gemm_core64<0>(ctx, 1024, m0, WFt + n0 * 1024, 1024, 1024, Alds, Blds, acc);

    const int tid = threadIdx.x, lid = tid & 63, wv = tid >> 6;
    const int wm = (wv >> 1) * 64, wn = (wv & 1) * 64, g = lid >> 4, r15 = lid & 15;
    #pragma unroll
    for (int nj = 0; nj < 4; ++nj) {
        const int col = n0 + wn + nj * 16 + r15;
        const float bv = bfc[col];
        #pragma unroll
        for (int mi = 0; mi < 4; ++mi)
            #pragma unroll
            for (int j = 0; j < 4; ++j) {
                const int row = m0 + wm + mi * 16 + g * 4 + j;
                out[(size_t)row * 1024 + col] = acc[mi][nj][j] + bv;
            }
    }
}

// ---------------------------------------------------------------------------
// Workspace (64 MiB), byte-exact offsets; lifetimes guarantee alias safety:
//   qx4 @0  kx4 @8M  vT @16M  WFt @24M
//   Qh @26M  Kh @34M  Vh @42M  WQt @50M  WKt @52M  WVt @54M  CTq @56M
//   After proj (Qh..WVt dead):  XtQ @26M (8.02M)  XtK @34.03M  CTk @42.05M
//   After conv: ctx @26M (over dead XtQ; ends before XtK which is also dead)
// ---------------------------------------------------------------------------
extern "C" void kernel_launch(void* const* d_in, const int* in_sizes, int n_in,
                              void* d_out, int out_size, void* d_ws, size_t ws_size,
                              hipStream_t stream)
{
    (void)in_sizes; (void)n_in; (void)out_size; (void)ws_size;
    const float* Q     = (const float*)d_in[0];
    const float* K     = (const float*)d_in[1];
    const float* V     = (const float*)d_in[2];
    // d_in[3] = attn_mask (unused by reference)
    const float* WQ    = (const float*)d_in[4];
    const float* bQ    = (const float*)d_in[5];
    const float* WK    = (const float*)d_in[6];
    const float* bK    = (const float*)d_in[7];
    const float* WV    = (const float*)d_in[8];
    const float* bV    = (const float*)d_in[9];
    const float* Wfc   = (const float*)d_in[10];
    const float* bfc   = (const float*)d_in[11];
    const float* convq = (const float*)d_in[12];
    const float* convk = (const float*)d_in[13];
    const float* w     = (const float*)d_in[14];

    char* ws = (char*)d_ws;
    f16* qx4  = (f16*)(ws + 0);
    f16* kx4  = (f16*)(ws + 8388608);
    f16* vT   = (f16*)(ws + 16777216);
    f16* WFt  = (f16*)(ws + 25165824);
    f16* Qh   = (f16*)(ws + 27262976);
    f16* Kh   = (f16*)(ws + 35651584);
    f16* Vh   = (f16*)(ws + 44040192);
    f16* WQt  = (f16*)(ws + 52428800);
    f16* WKt  = (f16*)(ws + 54525952);
    f16* WVt  = (f16*)(ws + 56623104);
    f16* CTq  = (f16*)(ws + 58720256);
    f16* XtQ  = (f16*)(ws + 27262976);  // over dead Qh (+Kh head)
    f16* XtK  = (f16*)(ws + 35676160);  // over dead Kh (+Vh head)
    f16* CTk  = (f16*)(ws + 44089344);  // over dead Vh (+WQt head)
    f16* ctxb = (f16*)(ws + 27262976);  // over dead XtQ

    dim3 b256(256), bT(32, 8);

    // 1) fp32 -> fp16 inputs
    k_cvt<<<4096, b256, 0, stream>>>(Q, Qh, 1048576);
    k_cvt<<<4096, b256, 0, stream>>>(K, Kh, 1048576);
    k_cvt<<<4096, b256, 0, stream>>>(V, Vh, 1048576);
    // 2) weights -> transposed fp16
    k_transpose_cvt<<<dim3(32, 32), bT, 0, stream>>>(WQ, WQt, 1024, 1024);
    k_transpose_cvt<<<dim3(32, 32), bT, 0, stream>>>(WK, WKt, 1024, 1024);
    k_transpose_cvt<<<dim3(32, 32), bT, 0, stream>>>(WV, WVt, 1024, 1024);
    k_transpose_cvt<<<dim3(32, 32), bT, 0, stream>>>(Wfc, WFt, 1024, 1024);
    // 3) projections -> qx4, kx4, vT
    k_gemm_proj<<<dim3(8, 32, 3), b256, 0, stream>>>(Qh, Kh, Vh, WQt, WKt, WVt,
                                                     bQ, bK, bV, qx4, kx4, vT);
    // 4) conv A-operand: transpose + zero-pad (over dead Qh/Kh/Vh)
    k_transpose_pad<<<dim3(32, 33, 8), bT, 0, stream>>>(qx4, kx4, XtQ, XtK);
    // 5) conv weights -> CTq, CTk
    k_transpose_cvt<<<dim3(128, 32), bT, 0, stream>>>(convq, CTq, 1024, 4096);
    k_transpose_cvt<<<dim3(128, 32), bT, 0, stream>>>(convk, CTk, 1024, 4096);
    // 6) fused conv GEMM + residual in place (both tensors)
    k_gemm_conv<<<dim3(8, 8, 8), b256, 0, stream>>>(XtQ, XtK, CTq, CTk,
                                                    qx4, kx4, w);
    // 7) flash attention -> ctx (XCD-friendly grid: x=bh)
    k_attn<<<dim3(64, 8), b256, 0, stream>>>(qx4, kx4, vT, ctxb);
    // 8) final projection -> f32 output
    k_gemm_final<<<dim3(8, 32), b256, 0, stream>>>(ctxb, WFt, bfc, (float*)d_out);
}

// Round 9
// 251.062 us; speedup vs baseline: 1.2282x; 1.2282x over previous
//
#include <hip/hip_runtime.h>
#include <hip/hip_bf16.h>

typedef _Float16 f16;
typedef _Float16 f16x2 __attribute__((ext_vector_type(2)));
typedef _Float16 f16x4 __attribute__((ext_vector_type(4)));
typedef _Float16 f16x8 __attribute__((ext_vector_type(8)));
typedef float f32x4 __attribute__((ext_vector_type(4)));

// cvt_pkrtz returns __fp16 ext_vector(2); re-cast to our f16x2 (same bits).
__device__ __forceinline__ f16x2 pkrtz(float a, float b) {
    auto r = __builtin_amdgcn_cvt_pkrtz(a, b);
    f16x2 o; o[0] = (f16)r[0]; o[1] = (f16)r[1];
    return o;
}

#define XT_ROWS 1027
#define XT_BSTRIDE (XT_ROWS * 1024)   // elems per batch

// ---------------------------------------------------------------------------
// global -> LDS direct (16B per lane, wave-uniform LDS base + lane*16)
// ---------------------------------------------------------------------------
__device__ __forceinline__ void gload16(const f16* g, f16* l) {
    __builtin_amdgcn_global_load_lds(
        (const __attribute__((address_space(1))) void*)g,
        (__attribute__((address_space(3))) void*)l, 16, 0, 0);
}

// ---------------------------------------------------------------------------
// Stage a 128x64 f16 tile from row-major src (ld elems) into 16KB LDS.
// XOR-swizzle: LDS slot (row, cs) holds tile(row, (cs^(row&7))*8 .. +8).
// Linear LDS dest (gload_lds requirement); swizzle applied on the SOURCE col
// and identically on the read side (involution) -> conflict-free ds_read_b128.
// ---------------------------------------------------------------------------
__device__ __forceinline__ void stage_tile(const f16* src, int ld, f16* lds)
{
    const int tid = threadIdx.x;
    const int w512 = (tid >> 6) << 9;          // wave base (f16 elems)
    #pragma unroll
    for (int q = 0; q < 4; ++q) {
        const int s = q * 256 + tid;           // 16B slot id, 0..1023
        const int row = s >> 3;
        const int col = ((s & 7) ^ (row & 7)) << 3;
        gload16(src + row * ld + col, lds + (q << 11) + w512);
    }
}

// ---------------------------------------------------------------------------
// GEMM core, reg-prefetch pipelined: C(128x128) += A(128xK) * Bt(128xK)^T.
// Per k-step: ds_read whole tile -> regs; lgkmcnt(0); s_barrier (raw! no
// vmcnt drain); issue next tile's global_load_lds; MFMA on regs (overlaps
// the loads); vmcnt(0); s_barrier.  BK=64, 32KB LDS, XOR-swizzled.
// CONV=1: A row base = m0 + (k0>>10) into zero-padded Xt, col = k0&1023.
// 256 threads = 4 waves (2x2), each wave 64x64 = 4x4 frags of 16x16x32.
// ---------------------------------------------------------------------------
template <int CONV>
__device__ __forceinline__ void gemm_core64(
    const f16* __restrict__ A, int lda, int m0,
    const f16* __restrict__ Bt, int ldb, int K,
    f16* Alds, f16* Blds, f32x4 acc[4][4])
{
    const int tid = threadIdx.x;
    const int lid = tid & 63;
    const int wv  = tid >> 6;
    const int wm  = (wv >> 1) * 64;
    const int wn  = (wv & 1) * 64;
    const int g   = lid >> 4;
    const int r15 = lid & 15;

    // prologue: stage tile 0 (k0=0 -> conv f=0, col=0)
    stage_tile(A + m0 * lda, lda, Alds);
    stage_tile(Bt, ldb, Blds);
    asm volatile("s_waitcnt vmcnt(0)" ::: "memory");
    __builtin_amdgcn_s_barrier();

    for (int k0 = 0; k0 < K; k0 += 64) {
        // 1) ds_read the entire tile into registers
        f16x8 af[2][4], bf[2][4];
        #pragma unroll
        for (int kc = 0; kc < 2; ++kc) {
            #pragma unroll
            for (int mi = 0; mi < 4; ++mi) {
                const int row = wm + mi * 16 + r15;
                af[kc][mi] = *(const f16x8*)(Alds + row * 64 +
                                             (((kc * 4 + g) ^ (row & 7)) << 3));
            }
            #pragma unroll
            for (int nj = 0; nj < 4; ++nj) {
                const int row = wn + nj * 16 + r15;
                bf[kc][nj] = *(const f16x8*)(Blds + row * 64 +
                                             (((kc * 4 + g) ^ (row & 7)) << 3));
            }
        }
        asm volatile("s_waitcnt lgkmcnt(0)" ::: "memory");
        __builtin_amdgcn_sched_barrier(0);
        __builtin_amdgcn_s_barrier();          // all waves done reading LDS
        // 2) issue next tile's async loads (fly under the MFMAs)
        const int k1 = k0 + 64;
        if (k1 < K) {
            const f16* Asrc;
            if (CONV) Asrc = A + (m0 + (k1 >> 10)) * lda + (k1 & 1023);
            else      Asrc = A + m0 * lda + k1;
            stage_tile(Asrc, lda, Alds);
            stage_tile(Bt + k1, ldb, Blds);
        }
        __builtin_amdgcn_sched_barrier(0);
        // 3) MFMA on registers
        #pragma unroll
        for (int kc = 0; kc < 2; ++kc)
            #pragma unroll
            for (int mi = 0; mi < 4; ++mi)
                #pragma unroll
                for (int nj = 0; nj < 4; ++nj)
                    acc[mi][nj] = __builtin_amdgcn_mfma_f32_16x16x32_f16(
                        af[kc][mi], bf[kc][nj], acc[mi][nj], 0, 0, 0);
        __builtin_amdgcn_sched_barrier(0);
        // 4) loads landed; LDS ready for next iteration's ds_read
        asm volatile("s_waitcnt vmcnt(0)" ::: "memory");
        __builtin_amdgcn_s_barrier();
    }
}

// ---------------------------------------------------------------------------
// fp32 -> fp16 elementwise convert (float4 -> f16x4)
// ---------------------------------------------------------------------------
__global__ __launch_bounds__(256) void k_cvt(const float* __restrict__ in,
                                             f16* __restrict__ out, int n4)
{
    int i = blockIdx.x * 256 + threadIdx.x;
    if (i < n4) {
        float4 v = ((const float4*)in)[i];
        f16x4 o;
        o[0] = (f16)v.x; o[1] = (f16)v.y; o[2] = (f16)v.z; o[3] = (f16)v.w;
        ((f16x4*)out)[i] = o;
    }
}

// ---------------------------------------------------------------------------
// Transpose + convert: in (R x C) f32 -> out (C x R) f16.  R,C multiples of 32.
// ---------------------------------------------------------------------------
__global__ __launch_bounds__(256) void k_transpose_cvt(const float* __restrict__ in,
                                                       f16* __restrict__ out,
                                                       int R, int C)
{
    __shared__ float tile[32][33];
    int c0 = blockIdx.x * 32, r0 = blockIdx.y * 32;
    int tx = threadIdx.x, ty = threadIdx.y;
    #pragma unroll
    for (int i = ty; i < 32; i += 8)
        tile[i][tx] = in[(size_t)(r0 + i) * C + c0 + tx];
    __syncthreads();
    #pragma unroll
    for (int i = ty; i < 32; i += 8)
        out[(size_t)(c0 + i) * R + r0 + tx] = (f16)tile[tx][i];
}

// ---------------------------------------------------------------------------
// Transpose + zero-pad for the conv A-operand.
// in : per-batch (1024 c x 1024 t) f16; out: per-batch (1027 t' x 1024 c),
// out[t'][c] = in[c][t'-2] (rows t'<2 and t'>=1026 zero).
// grid (32, 33, 8): z = tensor*4 + batch.
// ---------------------------------------------------------------------------
__global__ __launch_bounds__(256) void k_transpose_pad(
    const f16* __restrict__ qx4, const f16* __restrict__ kx4,
    f16* __restrict__ XtQ, f16* __restrict__ XtK)
{
    int z = blockIdx.z, b = z & 3, ten = z >> 2;
    const f16* in = (ten ? kx4 : qx4) + (size_t)b * 1048576;
    f16* out = (ten ? XtK : XtQ) + (size_t)b * XT_BSTRIDE;
    __shared__ f16 tile[32][33];
    int c0 = blockIdx.x * 32;
    int tp0 = blockIdx.y * 32;
    int tx = threadIdx.x, ty = threadIdx.y;
    #pragma unroll
    for (int i = ty; i < 32; i += 8) {
        int t = tp0 + tx - 2;
        tile[i][tx] = (t >= 0 && t < 1024) ? in[(c0 + i) * 1024 + t] : (f16)0.f;
    }
    __syncthreads();
    #pragma unroll
    for (int i = ty; i < 32; i += 8) {
        int tp = tp0 + i;
        if (tp < XT_ROWS) out[tp * 1024 + c0 + tx] = tile[tx][i];
    }
}

// ---------------------------------------------------------------------------
// Projection GEMMs: z=0: q -> qx4 ; z=1: k -> kx4 ; z=2: v -> vT
// qx4/kx4: [b][h][l][d] ; vT: [b][h][d][l]
// ---------------------------------------------------------------------------
__global__ __launch_bounds__(256) void k_gemm_proj(
    const f16* __restrict__ Qh, const f16* __restrict__ Kh, const f16* __restrict__ Vh,
    const f16* __restrict__ WQt, const f16* __restrict__ WKt, const f16* __restrict__ WVt,
    const float* __restrict__ bQ, const float* __restrict__ bK, const float* __restrict__ bV,
    f16* __restrict__ qx4, f16* __restrict__ kx4, f16* __restrict__ vT)
{
    __shared__ __align__(16) f16 Alds[128 * 64];
    __shared__ __align__(16) f16 Blds[128 * 64];
    const int z = blockIdx.z;
    const f16* A  = z == 0 ? Qh : z == 1 ? Kh : Vh;
    const f16* Bt = z == 0 ? WQt : z == 1 ? WKt : WVt;
    const float* bias = z == 0 ? bQ : z == 1 ? bK : bV;
    f16* dst = z == 0 ? qx4 : z == 1 ? kx4 : vT;
    const int m0 = blockIdx.y * 128, n0 = blockIdx.x * 128;
    f32x4 acc[4][4] = {};
    gemm_core64<0>(A, 1024, m0, Bt + n0 * 1024, 1024, 1024, Alds, Blds, acc);

    const int tid = threadIdx.x, lid = tid & 63, wv = tid >> 6;
    const int wm = (wv >> 1) * 64, wn = (wv & 1) * 64, g = lid >> 4, r15 = lid & 15;
    #pragma unroll
    for (int nj = 0; nj < 4; ++nj) {
        const int col = n0 + wn + nj * 16 + r15;
        const float bv = bias[col];
        const int h = col >> 6, d = col & 63;
        #pragma unroll
        for (int mi = 0; mi < 4; ++mi)
            #pragma unroll
            for (int j = 0; j < 4; ++j) {
                const int row = m0 + wm + mi * 16 + g * 4 + j;
                const int b = row >> 10, l = row & 1023;
                const float v = acc[mi][nj][j] + bv;
                const int off = b * 1048576 + h * 65536 +
                                (z == 2 ? (d * 1024 + l) : (l * 64 + d));
                dst[off] = (f16)v;
            }
    }
}

// ---------------------------------------------------------------------------
// Fused conv GEMM (both tensors): Out[t][o] = sum_{f<flen,c} Xt[t+f][c] *
// CT[o][f*1024+c], then += residual IN PLACE.  grid (8, 8, 8): z = ten*4+b.
// ---------------------------------------------------------------------------
__global__ __launch_bounds__(256) void k_gemm_conv(
    const f16* __restrict__ XtQ, const f16* __restrict__ XtK,
    const f16* __restrict__ CTq, const f16* __restrict__ CTk,
    f16* __restrict__ qx4, f16* __restrict__ kx4,
    const float* __restrict__ wvec)
{
    __shared__ __align__(16) f16 Alds[128 * 64];
    __shared__ __align__(16) f16 Blds[128 * 64];
    const int z = blockIdx.z, b = z & 3, ten = z >> 2;
    const f16* Xt = (ten ? XtK : XtQ) + (size_t)b * XT_BSTRIDE;
    const f16* CT = ten ? CTk : CTq;
    f16* dst = (ten ? kx4 : qx4) + (size_t)b * 1048576;

    // flen = FILTER_LENGTHS[argmax([2,4]*w)] ; argmax ties -> first index
    const int flen = (2.f * wvec[0] >= 4.f * wvec[1]) ? 2 : 4;
    const int K = flen << 10;

    const int m0 = blockIdx.y * 128, n0 = blockIdx.x * 128;
    f32x4 acc[4][4] = {};
    gemm_core64<1>(Xt, 1024, m0, CT + n0 * 4096, 4096, K, Alds, Blds, acc);

    const int tid = threadIdx.x, lid = tid & 63, wv = tid >> 6;
    const int wm = (wv >> 1) * 64, wn = (wv & 1) * 64, g = lid >> 4, r15 = lid & 15;
    #pragma unroll
    for (int nj = 0; nj < 4; ++nj) {
        const int col = n0 + wn + nj * 16 + r15;
        #pragma unroll
        for (int mi = 0; mi < 4; ++mi)
            #pragma unroll
            for (int j = 0; j < 4; ++j) {
                const int row = m0 + wm + mi * 16 + g * 4 + j;
                const int i = row * 1024 + col;
                dst[i] = (f16)(acc[mi][nj][j] + (float)dst[i]);
            }
    }
}

// ---------------------------------------------------------------------------
// Flash attention, shuffle-free inner loop (round-7 body), XCD-friendly grid:
// grid (64 bh, 8 qt) -> the 8 blocks sharing a head's K/V land on one XCD
// (linear id mod 8 == bh mod 8; per-XCD L2 holds 8 heads x 256KB = 2MB).
// 4 independent waves x 32 q-rows.  Swapped QK^T; constant-shift exp;
// deferred row-sum; sigma' k-slot bijection on both PV operands.
// ---------------------------------------------------------------------------
__global__ __launch_bounds__(256) void k_attn(
    const f16* __restrict__ qn, const f16* __restrict__ kn,
    const f16* __restrict__ vT, f16* __restrict__ ctx)
{
    const int bh = blockIdx.x, b = bh >> 4, h = bh & 15;
    const f16* Qp = qn + (size_t)b * 1048576 + h * 65536;
    const f16* Kp = kn + (size_t)b * 1048576 + h * 65536;
    const f16* Vp = vT + (size_t)b * 1048576 + h * 65536;
    const int tid = threadIdx.x, lid = tid & 63, wv = tid >> 6;
    const int g = lid >> 4, r15 = lid & 15;
    const int q0 = blockIdx.y * 128 + wv * 32;

    __shared__ __align__(16) f16 Olds[4][32][72];

    // Q B-fragments (2 q-halves x 2 d-chunks), pre-scaled by 1/8 (exact)
    f16x8 qf[2][2];
    #pragma unroll
    for (int qh = 0; qh < 2; ++qh)
        #pragma unroll
        for (int kc = 0; kc < 2; ++kc) {
            f16x8 t = *(const f16x8*)(Qp + (q0 + qh * 16 + r15) * 64 + kc * 32 + g * 8);
            #pragma unroll
            for (int e = 0; e < 8; ++e) t[e] = t[e] * (f16)0.125f;
            qf[qh][kc] = t;
        }

    f32x4 o[2][4] = {};     // O[q=qh*16+r15][d=db*16+g*4+j]
    f32x4 lsum[2] = {};     // per-lane partial row sums

    for (int t = 0; t < 16; ++t) {
        const int kv0 = t * 64;
        // K A-fragments: K[kv0+nj*16+r15][kc*32+g*8+e]
        f16x8 kf[4][2];
        #pragma unroll
        for (int nj = 0; nj < 4; ++nj)
            #pragma unroll
            for (int kc = 0; kc < 2; ++kc)
                kf[nj][kc] = *(const f16x8*)(Kp + (kv0 + nj * 16 + r15) * 64 + kc * 32 + g * 8);
        // V A-fragments with sigma': va[db][ch][e] = V[kv0+ch*32+sigma(g,e)][db*16+r15]
        f16x8 va[4][2];
        #pragma unroll
        for (int db = 0; db < 4; ++db)
            #pragma unroll
            for (int ch = 0; ch < 2; ++ch) {
                const f16* vp = Vp + (db * 16 + r15) * 1024 + kv0 + ch * 32 + g * 4;
                f16x4 lo = *(const f16x4*)vp;
                f16x4 hi = *(const f16x4*)(vp + 16);
                f16x8 v8;
                v8[0] = lo[0]; v8[1] = lo[1]; v8[2] = lo[2]; v8[3] = lo[3];
                v8[4] = hi[0]; v8[5] = hi[1]; v8[6] = hi[2]; v8[7] = hi[3];
                va[db][ch] = v8;
            }
        // QK^T (swapped): sacc[qh][nj], col=q=r15, row=k=g*4+j (+nj*16)
        f32x4 sacc[2][4] = {};
        #pragma unroll
        for (int nj = 0; nj < 4; ++nj)
            #pragma unroll
            for (int kc = 0; kc < 2; ++kc) {
                sacc[0][nj] = __builtin_amdgcn_mfma_f32_16x16x32_f16(
                    kf[nj][kc], qf[0][kc], sacc[0][nj], 0, 0, 0);
                sacc[1][nj] = __builtin_amdgcn_mfma_f32_16x16x32_f16(
                    kf[nj][kc], qf[1][kc], sacc[1][nj], 0, 0, 0);
            }
        // exp(s-2), accumulate row-sum partials, pack to f16 B-fragments
        #pragma unroll
        for (int qh = 0; qh < 2; ++qh) {
            f32x4 pe[4];
            #pragma unroll
            for (int nj = 0; nj < 4; ++nj) {
                #pragma unroll
                for (int j = 0; j < 4; ++j)
                    pe[nj][j] = __expf(sacc[qh][nj][j] - 2.0f);
                lsum[qh] += pe[nj];
            }
            f16x8 pb[2];
            #pragma unroll
            for (int ch = 0; ch < 2; ++ch) {
                union { f16x2 h2[4]; f16x8 v8; } u;
                u.h2[0] = pkrtz(pe[2 * ch][0], pe[2 * ch][1]);
                u.h2[1] = pkrtz(pe[2 * ch][2], pe[2 * ch][3]);
                u.h2[2] = pkrtz(pe[2 * ch + 1][0], pe[2 * ch + 1][1]);
                u.h2[3] = pkrtz(pe[2 * ch + 1][2], pe[2 * ch + 1][3]);
                pb[ch] = u.v8;
            }
            // PV: O^T[d][q] += V^T x P^T  (both operands in sigma' order)
            #pragma unroll
            for (int db = 0; db < 4; ++db)
                #pragma unroll
                for (int ch = 0; ch < 2; ++ch)
                    o[qh][db] = __builtin_amdgcn_mfma_f32_16x16x32_f16(
                        va[db][ch], pb[ch], o[qh][db], 0, 0, 0);
        }
    }

    // Finalize row sums: in-lane horizontal + reduce over g-groups (xor 16,32)
    float inv[2];
    #pragma unroll
    for (int qh = 0; qh < 2; ++qh) {
        float lr = lsum[qh][0] + lsum[qh][1] + lsum[qh][2] + lsum[qh][3];
        lr += __shfl_xor(lr, 16);
        lr += __shfl_xor(lr, 32);
        inv[qh] = 1.0f / lr;
    }
    // Normalize, transpose via per-wave LDS slice, coalesced store.
    #pragma unroll
    for (int qh = 0; qh < 2; ++qh)
        #pragma unroll
        for (int db = 0; db < 4; ++db) {
            const int row = qh * 16 + r15, col = db * 16 + g * 4;
            *(f16x2*)&Olds[wv][row][col] =
                pkrtz(o[qh][db][0] * inv[qh], o[qh][db][1] * inv[qh]);
            *(f16x2*)&Olds[wv][row][col + 2] =
                pkrtz(o[qh][db][2] * inv[qh], o[qh][db][3] * inv[qh]);
        }
    asm volatile("s_waitcnt lgkmcnt(0)" ::: "memory");
    __builtin_amdgcn_sched_barrier(0);
    #pragma unroll
    for (int p = 0; p < 4; ++p) {
        const int row = p * 8 + (lid >> 3);
        const int c8 = (lid & 7) * 8;
        f16x8 v = *(const f16x8*)&Olds[wv][row][c8];
        *(f16x8*)(ctx + (size_t)b * 1048576 + (q0 + row) * 1024 + h * 64 + c8) = v;
    }
}

// ---------------------------------------------------------------------------
// Final GEMM: out = ctx @ Wfc + bfc, output FLOAT32 (B,L,1024) row-major.
// ---------------------------------------------------------------------------
__global__ __launch_bounds__(256) void k_gemm_final(
    const f16* __restrict__ ctx, const f16* __restrict__ WFt,
    const float* __restrict__ bfc, float* __restrict__ out)
{
    __shared__ __align__(16) f16 Alds[128 * 64];
    __shared__ __align__(16) f16 Blds[128 * 64];
    const int m0 = blockIdx.y * 128, n0 = blockIdx.x * 128;
    f32x4 acc[4][4] = {};
    gemm_core64<0>(ctx, 1024, m0, WFt + n0 * 1024, 1024, 1024, Alds, Blds, acc);

    const int tid = threadIdx.x, lid = tid & 63, wv = tid >> 6;
    const int wm = (wv >> 1) * 64, wn = (wv & 1) * 64, g = lid >> 4, r15 = lid & 15;
    #pragma unroll
    for (int nj = 0; nj < 4; ++nj) {
        const int col = n0 + wn + nj * 16 + r15;
        const float bv = bfc[col];
        #pragma unroll
        for (int mi = 0; mi < 4; ++mi)
            #pragma unroll
            for (int j = 0; j < 4; ++j) {
                const int row = m0 + wm + mi * 16 + g * 4 + j;
                out[(size_t)row * 1024 + col] = acc[mi][nj][j] + bv;
            }
    }
}

// ---------------------------------------------------------------------------
// Workspace (64 MiB), byte-exact offsets; lifetimes guarantee alias safety:
//   qx4 @0  kx4 @8M  vT @16M  WFt @24M
//   Qh @26M  Kh @34M  Vh @42M  WQt @50M  WKt @52M  WVt @54M  CTq @56M
//   After proj (Qh..WVt dead):  XtQ @26M (8.02M)  XtK @34.03M  CTk @42.05M
//   After conv: ctx @26M (over dead XtQ; ends before XtK which is also dead)
// ---------------------------------------------------------------------------
extern "C" void kernel_launch(void* const* d_in, const int* in_sizes, int n_in,
                              void* d_out, int out_size, void* d_ws, size_t ws_size,
                              hipStream_t stream)
{
    (void)in_sizes; (void)n_in; (void)out_size; (void)ws_size;
    const float* Q     = (const float*)d_in[0];
    const float* K     = (const float*)d_in[1];
    const float* V     = (const float*)d_in[2];
    // d_in[3] = attn_mask (unused by reference)
    const float* WQ    = (const float*)d_in[4];
    const float* bQ    = (const float*)d_in[5];
    const float* WK    = (const float*)d_in[6];
    const float* bK    = (const float*)d_in[7];
    const float* WV    = (const float*)d_in[8];
    const float* bV    = (const float*)d_in[9];
    const float* Wfc   = (const float*)d_in[10];
    const float* bfc   = (const float*)d_in[11];
    const float* convq = (const float*)d_in[12];
    const float* convk = (const float*)d_in[13];
    const float* w     = (const float*)d_in[14];

    char* ws = (char*)d_ws;
    f16* qx4  = (f16*)(ws + 0);
    f16* kx4  = (f16*)(ws + 8388608);
    f16* vT   = (f16*)(ws + 16777216);
    f16* WFt  = (f16*)(ws + 25165824);
    f16* Qh   = (f16*)(ws + 27262976);
    f16* Kh   = (f16*)(ws + 35651584);
    f16* Vh   = (f16*)(ws + 44040192);
    f16* WQt  = (f16*)(ws + 52428800);
    f16* WKt  = (f16*)(ws + 54525952);
    f16* WVt  = (f16*)(ws + 56623104);
    f16* CTq  = (f16*)(ws + 58720256);
    f16* XtQ  = (f16*)(ws + 27262976);  // over dead Qh (+Kh head)
    f16* XtK  = (f16*)(ws + 35676160);  // over dead Kh (+Vh head)
    f16* CTk  = (f16*)(ws + 44089344);  // over dead Vh (+WQt head)
    f16* ctxb = (f16*)(ws + 27262976);  // over dead XtQ

    dim3 b256(256), bT(32, 8);

    // 1) fp32 -> fp16 inputs
    k_cvt<<<4096, b256, 0, stream>>>(Q, Qh, 1048576);
    k_cvt<<<4096, b256, 0, stream>>>(K, Kh, 1048576);
    k_cvt<<<4096, b256, 0, stream>>>(V, Vh, 1048576);
    // 2) weights -> transposed fp16
    k_transpose_cvt<<<dim3(32, 32), bT, 0, stream>>>(WQ, WQt, 1024, 1024);
    k_transpose_cvt<<<dim3(32, 32), bT, 0, stream>>>(WK, WKt, 1024, 1024);
    k_transpose_cvt<<<dim3(32, 32), bT, 0, stream>>>(WV, WVt, 1024, 1024);
    k_transpose_cvt<<<dim3(32, 32), bT, 0, stream>>>(Wfc, WFt, 1024, 1024);
    // 3) projections -> qx4, kx4, vT
    k_gemm_proj<<<dim3(8, 32, 3), b256, 0, stream>>>(Qh, Kh, Vh, WQt, WKt, WVt,
                                                     bQ, bK, bV, qx4, kx4, vT);
    // 4) conv A-operand: transpose + zero-pad (over dead Qh/Kh/Vh)
    k_transpose_pad<<<dim3(32, 33, 8), bT, 0, stream>>>(qx4, kx4, XtQ, XtK);
    // 5) conv weights -> CTq, CTk
    k_transpose_cvt<<<dim3(128, 32), bT, 0, stream>>>(convq, CTq, 1024, 4096);
    k_transpose_cvt<<<dim3(128, 32), bT, 0, stream>>>(convk, CTk, 1024, 4096);
    // 6) fused conv GEMM + residual in place (both tensors)
    k_gemm_conv<<<dim3(8, 8, 8), b256, 0, stream>>>(XtQ, XtK, CTq, CTk,
                                                    qx4, kx4, w);
    // 7) flash attention -> ctx (XCD-friendly grid: x=bh)
    k_attn<<<dim3(64, 8), b256, 0, stream>>>(qx4, kx4, vT, ctxb);
    // 8) final projection -> f32 output
    k_gemm_final<<<dim3(8, 32), b256, 0, stream>>>(ctxb, WFt, bfc, (float*)d_out);
}

// Round 11
// 249.118 us; speedup vs baseline: 1.2378x; 1.0078x over previous
//
#include <hip/hip_runtime.h>
#include <hip/hip_bf16.h>

typedef _Float16 f16;
typedef _Float16 f16x2 __attribute__((ext_vector_type(2)));
typedef _Float16 f16x4 __attribute__((ext_vector_type(4)));
typedef _Float16 f16x8 __attribute__((ext_vector_type(8)));
typedef float f32x4 __attribute__((ext_vector_type(4)));

// cvt_pkrtz returns __fp16 ext_vector(2); re-cast to our f16x2 (same bits).
__device__ __forceinline__ f16x2 pkrtz(float a, float b) {
    auto r = __builtin_amdgcn_cvt_pkrtz(a, b);
    f16x2 o; o[0] = (f16)r[0]; o[1] = (f16)r[1];
    return o;
}

#define XT_ROWS 1027
#define XT_BSTRIDE (XT_ROWS * 1024)   // elems per batch

// ---------------------------------------------------------------------------
// global -> LDS direct (16B per lane, wave-uniform LDS base + lane*16)
// ---------------------------------------------------------------------------
__device__ __forceinline__ void gload16(const f16* g, f16* l) {
    __builtin_amdgcn_global_load_lds(
        (const __attribute__((address_space(1))) void*)g,
        (__attribute__((address_space(3))) void*)l, 16, 0, 0);
}

// ---------------------------------------------------------------------------
// Stage a 128x64 f16 tile from row-major src (ld elems) into 16KB LDS.
// XOR-swizzle on the SOURCE col, same XOR on the read side (involution).
// ---------------------------------------------------------------------------
__device__ __forceinline__ void stage_tile(const f16* src, int ld, f16* lds)
{
    const int tid = threadIdx.x;
    const int w512 = (tid >> 6) << 9;          // wave base (f16 elems)
    #pragma unroll
    for (int q = 0; q < 4; ++q) {
        const int s = q * 256 + tid;           // 16B slot id, 0..1023
        const int row = s >> 3;
        const int col = ((s & 7) ^ (row & 7)) << 3;
        gload16(src + row * ld + col, lds + (q << 11) + w512);
    }
}

// ---------------------------------------------------------------------------
// GEMM core, reg-prefetch pipelined: C(128x128) += A(128xK) * Bt(128xK)^T.
// Per k-step: ds_read tile -> regs; lgkmcnt(0); s_barrier (raw); issue next
// tile's global_load_lds; MFMA on regs (overlaps loads); vmcnt(0); s_barrier.
// CONV=1: A row base = m0 + (k0>>10) into zero-padded Xt, col = k0&1023.
// ---------------------------------------------------------------------------
template <int CONV>
__device__ __forceinline__ void gemm_core64(
    const f16* __restrict__ A, int lda, int m0,
    const f16* __restrict__ Bt, int ldb, int K,
    f16* Alds, f16* Blds, f32x4 acc[4][4])
{
    const int tid = threadIdx.x;
    const int lid = tid & 63;
    const int wv  = tid >> 6;
    const int wm  = (wv >> 1) * 64;
    const int wn  = (wv & 1) * 64;
    const int g   = lid >> 4;
    const int r15 = lid & 15;

    // prologue: stage tile 0 (k0=0 -> conv f=0, col=0)
    stage_tile(A + m0 * lda, lda, Alds);
    stage_tile(Bt, ldb, Blds);
    asm volatile("s_waitcnt vmcnt(0)" ::: "memory");
    __builtin_amdgcn_s_barrier();

    for (int k0 = 0; k0 < K; k0 += 64) {
        // 1) ds_read the entire tile into registers
        f16x8 af[2][4], bf[2][4];
        #pragma unroll
        for (int kc = 0; kc < 2; ++kc) {
            #pragma unroll
            for (int mi = 0; mi < 4; ++mi) {
                const int row = wm + mi * 16 + r15;
                af[kc][mi] = *(const f16x8*)(Alds + row * 64 +
                                             (((kc * 4 + g) ^ (row & 7)) << 3));
            }
            #pragma unroll
            for (int nj = 0; nj < 4; ++nj) {
                const int row = wn + nj * 16 + r15;
                bf[kc][nj] = *(const f16x8*)(Blds + row * 64 +
                                             (((kc * 4 + g) ^ (row & 7)) << 3));
            }
        }
        asm volatile("s_waitcnt lgkmcnt(0)" ::: "memory");
        __builtin_amdgcn_sched_barrier(0);
        __builtin_amdgcn_s_barrier();          // all waves done reading LDS
        // 2) issue next tile's async loads (fly under the MFMAs)
        const int k1 = k0 + 64;
        if (k1 < K) {
            const f16* Asrc;
            if (CONV) Asrc = A + (m0 + (k1 >> 10)) * lda + (k1 & 1023);
            else      Asrc = A + m0 * lda + k1;
            stage_tile(Asrc, lda, Alds);
            stage_tile(Bt + k1, ldb, Blds);
        }
        __builtin_amdgcn_sched_barrier(0);
        // 3) MFMA on registers
        #pragma unroll
        for (int kc = 0; kc < 2; ++kc)
            #pragma unroll
            for (int mi = 0; mi < 4; ++mi)
                #pragma unroll
                for (int nj = 0; nj < 4; ++nj)
                    acc[mi][nj] = __builtin_amdgcn_mfma_f32_16x16x32_f16(
                        af[kc][mi], bf[kc][nj], acc[mi][nj], 0, 0, 0);
        __builtin_amdgcn_sched_barrier(0);
        // 4) loads landed; LDS ready for next iteration's ds_read
        asm volatile("s_waitcnt vmcnt(0)" ::: "memory");
        __builtin_amdgcn_s_barrier();
    }
}

// ---------------------------------------------------------------------------
// Fused fp32 -> fp16 convert for Q,K,V (grid 3*4096 blocks).
// ---------------------------------------------------------------------------
__global__ __launch_bounds__(256) void k_cvt_all(
    const float* __restrict__ Q, const float* __restrict__ K,
    const float* __restrict__ V, f16* __restrict__ Qh,
    f16* __restrict__ Kh, f16* __restrict__ Vh)
{
    const int bid = blockIdx.x;
    const int which = bid >> 12;
    const int i = (bid & 4095) * 256 + threadIdx.x;
    const float* in = which == 0 ? Q : which == 1 ? K : V;
    f16* out = which == 0 ? Qh : which == 1 ? Kh : Vh;
    float4 v = ((const float4*)in)[i];
    f16x4 o;
    o[0] = (f16)v.x; o[1] = (f16)v.y; o[2] = (f16)v.z; o[3] = (f16)v.w;
    ((f16x4*)out)[i] = o;
}

// ---------------------------------------------------------------------------
// Fused transpose+convert for the 4 1024x1024 weights.  grid (32,32,4).
// ---------------------------------------------------------------------------
__global__ __launch_bounds__(256) void k_wtrans(
    const float* __restrict__ WQ, const float* __restrict__ WK,
    const float* __restrict__ WV, const float* __restrict__ Wfc,
    f16* __restrict__ WQt, f16* __restrict__ WKt,
    f16* __restrict__ WVt, f16* __restrict__ WFt)
{
    const int z = blockIdx.z;
    const float* in = z == 0 ? WQ : z == 1 ? WK : z == 2 ? WV : Wfc;
    f16* out = z == 0 ? WQt : z == 1 ? WKt : z == 2 ? WVt : WFt;
    __shared__ float tile[32][33];
    int c0 = blockIdx.x * 32, r0 = blockIdx.y * 32;
    int tx = threadIdx.x, ty = threadIdx.y;
    #pragma unroll
    for (int i = ty; i < 32; i += 8)
        tile[i][tx] = in[(size_t)(r0 + i) * 1024 + c0 + tx];
    __syncthreads();
    #pragma unroll
    for (int i = ty; i < 32; i += 8)
        out[(size_t)(c0 + i) * 1024 + r0 + tx] = (f16)tile[tx][i];
}

// ---------------------------------------------------------------------------
// Fused transpose+convert for conv weights (1024 x 4096).  grid (128,32,2).
// NOTE: must launch AFTER projections — CTk overlays dead Vh/WQt.
// ---------------------------------------------------------------------------
__global__ __launch_bounds__(256) void k_ctrans(
    const float* __restrict__ convq, const float* __restrict__ convk,
    f16* __restrict__ CTq, f16* __restrict__ CTk)
{
    const float* in = blockIdx.z ? convk : convq;
    f16* out = blockIdx.z ? CTk : CTq;
    __shared__ float tile[32][33];
    int c0 = blockIdx.x * 32, r0 = blockIdx.y * 32;
    int tx = threadIdx.x, ty = threadIdx.y;
    #pragma unroll
    for (int i = ty; i < 32; i += 8)
        tile[i][tx] = in[(size_t)(r0 + i) * 4096 + c0 + tx];
    __syncthreads();
    #pragma unroll
    for (int i = ty; i < 32; i += 8)
        out[(size_t)(c0 + i) * 1024 + r0 + tx] = (f16)tile[tx][i];
}

// ---------------------------------------------------------------------------
// Transpose + zero-pad for the conv A-operand.
// out[t'][c] = in[c][t'-2] (rows t'<2 and t'>=1026 zero).  grid (32,33,8).
// ---------------------------------------------------------------------------
__global__ __launch_bounds__(256) void k_transpose_pad(
    const f16* __restrict__ qx4, const f16* __restrict__ kx4,
    f16* __restrict__ XtQ, f16* __restrict__ XtK)
{
    int z = blockIdx.z, b = z & 3, ten = z >> 2;
    const f16* in = (ten ? kx4 : qx4) + (size_t)b * 1048576;
    f16* out = (ten ? XtK : XtQ) + (size_t)b * XT_BSTRIDE;
    __shared__ f16 tile[32][33];
    int c0 = blockIdx.x * 32;
    int tp0 = blockIdx.y * 32;
    int tx = threadIdx.x, ty = threadIdx.y;
    #pragma unroll
    for (int i = ty; i < 32; i += 8) {
        int t = tp0 + tx - 2;
        tile[i][tx] = (t >= 0 && t < 1024) ? in[(c0 + i) * 1024 + t] : (f16)0.f;
    }
    __syncthreads();
    #pragma unroll
    for (int i = ty; i < 32; i += 8) {
        int tp = tp0 + i;
        if (tp < XT_ROWS) out[tp * 1024 + c0 + tx] = tile[tx][i];
    }
}

// ---------------------------------------------------------------------------
// Projection GEMMs: z=0: q -> qx4 ; z=1: k -> kx4 ; z=2: v -> vT
// ---------------------------------------------------------------------------
__global__ __launch_bounds__(256) void k_gemm_proj(
    const f16* __restrict__ Qh, const f16* __restrict__ Kh, const f16* __restrict__ Vh,
    const f16* __restrict__ WQt, const f16* __restrict__ WKt, const f16* __restrict__ WVt,
    const float* __restrict__ bQ, const float* __restrict__ bK, const float* __restrict__ bV,
    f16* __restrict__ qx4, f16* __restrict__ kx4, f16* __restrict__ vT)
{
    __shared__ __align__(16) f16 Alds[128 * 64];
    __shared__ __align__(16) f16 Blds[128 * 64];
    const int z = blockIdx.z;
    const f16* A  = z == 0 ? Qh : z == 1 ? Kh : Vh;
    const f16* Bt = z == 0 ? WQt : z == 1 ? WKt : WVt;
    const float* bias = z == 0 ? bQ : z == 1 ? bK : bV;
    f16* dst = z == 0 ? qx4 : z == 1 ? kx4 : vT;
    const int m0 = blockIdx.y * 128, n0 = blockIdx.x * 128;
    f32x4 acc[4][4] = {};
    gemm_core64<0>(A, 1024, m0, Bt + n0 * 1024, 1024, 1024, Alds, Blds, acc);

    const int tid = threadIdx.x, lid = tid & 63, wv = tid >> 6;
    const int wm = (wv >> 1) * 64, wn = (wv & 1) * 64, g = lid >> 4, r15 = lid & 15;
    #pragma unroll
    for (int nj = 0; nj < 4; ++nj) {
        const int col = n0 + wn + nj * 16 + r15;
        const float bv = bias[col];
        const int h = col >> 6, d = col & 63;
        #pragma unroll
        for (int mi = 0; mi < 4; ++mi)
            #pragma unroll
            for (int j = 0; j < 4; ++j) {
                const int row = m0 + wm + mi * 16 + g * 4 + j;
                const int b = row >> 10, l = row & 1023;
                const float v = acc[mi][nj][j] + bv;
                const int off = b * 1048576 + h * 65536 +
                                (z == 2 ? (d * 1024 + l) : (l * 64 + d));
                dst[off] = (f16)v;
            }
    }
}

// ---------------------------------------------------------------------------
// Fused conv GEMM + residual IN PLACE.  grid (8, 8, 8): z = ten*4+b.
// ---------------------------------------------------------------------------
__global__ __launch_bounds__(256) void k_gemm_conv(
    const f16* __restrict__ XtQ, const f16* __restrict__ XtK,
    const f16* __restrict__ CTq, const f16* __restrict__ CTk,
    f16* __restrict__ qx4, f16* __restrict__ kx4,
    const float* __restrict__ wvec)
{
    __shared__ __align__(16) f16 Alds[128 * 64];
    __shared__ __align__(16) f16 Blds[128 * 64];
    const int z = blockIdx.z, b = z & 3, ten = z >> 2;
    const f16* Xt = (ten ? XtK : XtQ) + (size_t)b * XT_BSTRIDE;
    const f16* CT = ten ? CTk : CTq;
    f16* dst = (ten ? kx4 : qx4) + (size_t)b * 1048576;

    // flen = FILTER_LENGTHS[argmax([2,4]*w)] ; argmax ties -> first index
    const int flen = (2.f * wvec[0] >= 4.f * wvec[1]) ? 2 : 4;
    const int K = flen << 10;

    const int m0 = blockIdx.y * 128, n0 = blockIdx.x * 128;
    f32x4 acc[4][4] = {};
    gemm_core64<1>(Xt, 1024, m0, CT + n0 * 4096, 4096, K, Alds, Blds, acc);

    const int tid = threadIdx.x, lid = tid & 63, wv = tid >> 6;
    const int wm = (wv >> 1) * 64, wn = (wv & 1) * 64, g = lid >> 4, r15 = lid & 15;
    #pragma unroll
    for (int nj = 0; nj < 4; ++nj) {
        const int col = n0 + wn + nj * 16 + r15;
        #pragma unroll
        for (int mi = 0; mi < 4; ++mi)
            #pragma unroll
            for (int j = 0; j < 4; ++j) {
                const int row = m0 + wm + mi * 16 + g * 4 + j;
                const int i = row * 1024 + col;
                dst[i] = (f16)(acc[mi][nj][j] + (float)dst[i]);
            }
    }
}

// ---------------------------------------------------------------------------
// Flash attention, KV-split partials.  grid (64 bh, 8 qt, 2 kvh).
// Each block: 8 KV tiles, writes UNNORMALIZED f32 O-partial + row-sum partial
// (constant-shift softmax has no running max -> partials combine by addition).
// Linear block id mod 8 == bh mod 8 -> K/V-sharing blocks on one XCD.
// 4 independent waves x 32 q-rows; swapped QK^T; sigma' k-slot bijection.
// ---------------------------------------------------------------------------
__global__ __launch_bounds__(256) void k_attn(
    const f16* __restrict__ qn, const f16* __restrict__ kn,
    const f16* __restrict__ vT, float* __restrict__ Opart,
    float* __restrict__ Lpart)
{
    const int bh = blockIdx.x, b = bh >> 4, h = bh & 15;
    const int kvh = blockIdx.z;
    const f16* Qp = qn + (size_t)b * 1048576 + h * 65536;
    const f16* Kp = kn + (size_t)b * 1048576 + h * 65536;
    const f16* Vp = vT + (size_t)b * 1048576 + h * 65536;
    const int tid = threadIdx.x, lid = tid & 63, wv = tid >> 6;
    const int g = lid >> 4, r15 = lid & 15;
    const int q0 = blockIdx.y * 128 + wv * 32;

    // Q B-fragments (2 q-halves x 2 d-chunks), pre-scaled by 1/8 (exact)
    f16x8 qf[2][2];
    #pragma unroll
    for (int qh = 0; qh < 2; ++qh)
        #pragma unroll
        for (int kc = 0; kc < 2; ++kc) {
            f16x8 t = *(const f16x8*)(Qp + (q0 + qh * 16 + r15) * 64 + kc * 32 + g * 8);
            #pragma unroll
            for (int e = 0; e < 8; ++e) t[e] = t[e] * (f16)0.125f;
            qf[qh][kc] = t;
        }

    f32x4 o[2][4] = {};     // O[q=qh*16+r15][d=db*16+g*4+j]  (unnormalized)
    f32x4 lsum[2] = {};     // per-lane partial row sums

    for (int t = 0; t < 8; ++t) {
        const int kv0 = kvh * 512 + t * 64;
        // K A-fragments: K[kv0+nj*16+r15][kc*32+g*8+e]
        f16x8 kf[4][2];
        #pragma unroll
        for (int nj = 0; nj < 4; ++nj)
            #pragma unroll
            for (int kc = 0; kc < 2; ++kc)
                kf[nj][kc] = *(const f16x8*)(Kp + (kv0 + nj * 16 + r15) * 64 + kc * 32 + g * 8);
        // V A-fragments with sigma': va[db][ch][e] = V[kv0+ch*32+sigma(g,e)][db*16+r15]
        f16x8 va[4][2];
        #pragma unroll
        for (int db = 0; db < 4; ++db)
            #pragma unroll
            for (int ch = 0; ch < 2; ++ch) {
                const f16* vp = Vp + (db * 16 + r15) * 1024 + kv0 + ch * 32 + g * 4;
                f16x4 lo = *(const f16x4*)vp;
                f16x4 hi = *(const f16x4*)(vp + 16);
                f16x8 v8;
                v8[0] = lo[0]; v8[1] = lo[1]; v8[2] = lo[2]; v8[3] = lo[3];
                v8[4] = hi[0]; v8[5] = hi[1]; v8[6] = hi[2]; v8[7] = hi[3];
                va[db][ch] = v8;
            }
        // QK^T (swapped): sacc[qh][nj], col=q=r15, row=k=g*4+j (+nj*16)
        f32x4 sacc[2][4] = {};
        #pragma unroll
        for (int nj = 0; nj < 4; ++nj)
            #pragma unroll
            for (int kc = 0; kc < 2; ++kc) {
                sacc[0][nj] = __builtin_amdgcn_mfma_f32_16x16x32_f16(
                    kf[nj][kc], qf[0][kc], sacc[0][nj], 0, 0, 0);
                sacc[1][nj] = __builtin_amdgcn_mfma_f32_16x16x32_f16(
                    kf[nj][kc], qf[1][kc], sacc[1][nj], 0, 0, 0);
            }
        // exp(s-2), accumulate row-sum partials, pack to f16 B-fragments
        #pragma unroll
        for (int qh = 0; qh < 2; ++qh) {
            f32x4 pe[4];
            #pragma unroll
            for (int nj = 0; nj < 4; ++nj) {
                #pragma unroll
                for (int j = 0; j < 4; ++j)
                    pe[nj][j] = __expf(sacc[qh][nj][j] - 2.0f);
                lsum[qh] += pe[nj];
            }
            f16x8 pb[2];
            #pragma unroll
            for (int ch = 0; ch < 2; ++ch) {
                union { f16x2 h2[4]; f16x8 v8; } u;
                u.h2[0] = pkrtz(pe[2 * ch][0], pe[2 * ch][1]);
                u.h2[1] = pkrtz(pe[2 * ch][2], pe[2 * ch][3]);
                u.h2[2] = pkrtz(pe[2 * ch + 1][0], pe[2 * ch + 1][1]);
                u.h2[3] = pkrtz(pe[2 * ch + 1][2], pe[2 * ch + 1][3]);
                pb[ch] = u.v8;
            }
            // PV: O^T[d][q] += V^T x P^T  (both operands in sigma' order)
            #pragma unroll
            for (int db = 0; db < 4; ++db)
                #pragma unroll
                for (int ch = 0; ch < 2; ++ch)
                    o[qh][db] = __builtin_amdgcn_mfma_f32_16x16x32_f16(
                        va[db][ch], pb[ch], o[qh][db], 0, 0, 0);
        }
    }

    // Partial row sums: in-lane horizontal + reduce over g-groups (xor 16,32)
    float* Op = Opart + (size_t)kvh * 4194304 + (size_t)b * 1048576;
    float* Lp = Lpart + kvh * 65536 + bh * 1024;
    #pragma unroll
    for (int qh = 0; qh < 2; ++qh) {
        float lr = lsum[qh][0] + lsum[qh][1] + lsum[qh][2] + lsum[qh][3];
        lr += __shfl_xor(lr, 16);
        lr += __shfl_xor(lr, 32);
        if (g == 0) Lp[q0 + qh * 16 + r15] = lr;
        #pragma unroll
        for (int db = 0; db < 4; ++db) {
            const int row = q0 + qh * 16 + r15;
            const int col = h * 64 + db * 16 + g * 4;
            *(f32x4*)(Op + (size_t)row * 1024 + col) = o[qh][db];
        }
    }
}

// ---------------------------------------------------------------------------
// Combine KV-split partials: ctx = (O0+O1)/(L0+L1), f16.  grid 4096 x 256.
// flat layout: (b<<20) + (l<<10) + (h<<6) + d
// ---------------------------------------------------------------------------
__global__ __launch_bounds__(256) void k_combine(
    const float* __restrict__ Opart, const float* __restrict__ Lpart,
    f16* __restrict__ ctx)
{
    const int i = blockIdx.x * 256 + threadIdx.x;   // 4-elem chunk id
    const int flat = i * 4;
    const int b = flat >> 20, l = (flat >> 10) & 1023, h = (flat >> 6) & 15;
    f32x4 o0 = *(const f32x4*)(Opart + flat);
    f32x4 o1 = *(const f32x4*)(Opart + 4194304 + flat);
    const int li = (b * 16 + h) * 1024 + l;
    const float inv = 1.0f / (Lpart[li] + Lpart[65536 + li]);
    union { f16x2 h2[2]; f16x4 v4; } u;
    u.h2[0] = pkrtz((o0[0] + o1[0]) * inv, (o0[1] + o1[1]) * inv);
    u.h2[1] = pkrtz((o0[2] + o1[2]) * inv, (o0[3] + o1[3]) * inv);
    *(f16x4*)(ctx + flat) = u.v4;
}

// ---------------------------------------------------------------------------
// Final GEMM: out = ctx @ Wfc + bfc, output FLOAT32 (B,L,1024) row-major.
// ---------------------------------------------------------------------------
__global__ __launch_bounds__(256) void k_gemm_final(
    const f16* __restrict__ ctx, const f16* __restrict__ WFt,
    const float* __restrict__ bfc, float* __restrict__ out)
{
    __shared__ __align__(16) f16 Alds[128 * 64];
    __shared__ __align__(16) f16 Blds[128 * 64];
    const int m0 = blockIdx.y * 128, n0 = blockIdx.x * 128;
    f32x4 acc[4][4] = {};
    gemm_core64<0>(ctx, 1024, m0, WFt + n0 * 1024, 1024, 1024, Alds, Blds, acc);

    const int tid = threadIdx.x, lid = tid & 63, wv = tid >> 6;
    const int wm = (wv >> 1) * 64, wn = (wv & 1) * 64, g = lid >> 4, r15 = lid & 15;
    #pragma unroll
    for (int nj = 0; nj < 4; ++nj) {
        const int col = n0 + wn + nj * 16 + r15;
        const float bv = bfc[col];
        #pragma unroll
        for (int mi = 0; mi < 4; ++mi)
            #pragma unroll
            for (int j = 0; j < 4; ++j) {
                const int row = m0 + wm + mi * 16 + g * 4 + j;
                out[(size_t)row * 1024 + col] = acc[mi][nj][j] + bv;
            }
    }
}

// ---------------------------------------------------------------------------
// Workspace (64 MiB), byte-exact offsets; lifetime schedule:
//   qx4 @0  kx4 @8M  vT @16M  WFt @24M (live: proj..final)
//   Qh @26M  Kh @34M  Vh @42M  WQt @50M  WKt @52M  WVt @54M (cvt/wtrans->proj)
//   CTq @56M (ctrans->conv; free region all along)
//   After proj: XtQ @26M  XtK @34.03M (pad->conv)
//               CTk @42.05M over dead Vh tail + WQt head (ctrans->conv)
//   After conv: Opart @26M (32M)  Lpart @58M+ (attn->combine; over dead
//               Xt/CTk and CTq tail)
//   After attn: ctx @0 over dead qx4 (combine->final)
//   ORDER MATTERS: k_ctrans must run AFTER k_gemm_proj (CTk overlays Vh/WQt).
// ---------------------------------------------------------------------------
extern "C" void kernel_launch(void* const* d_in, const int* in_sizes, int n_in,
                              void* d_out, int out_size, void* d_ws, size_t ws_size,
                              hipStream_t stream)
{
    (void)in_sizes; (void)n_in; (void)out_size; (void)ws_size;
    const float* Q     = (const float*)d_in[0];
    const float* K     = (const float*)d_in[1];
    const float* V     = (const float*)d_in[2];
    // d_in[3] = attn_mask (unused by reference)
    const float* WQ    = (const float*)d_in[4];
    const float* bQ    = (const float*)d_in[5];
    const float* WK    = (const float*)d_in[6];
    const float* bK    = (const float*)d_in[7];
    const float* WV    = (const float*)d_in[8];
    const float* bV    = (const float*)d_in[9];
    const float* Wfc   = (const float*)d_in[10];
    const float* bfc   = (const float*)d_in[11];
    const float* convq = (const float*)d_in[12];
    const float* convk = (const float*)d_in[13];
    const float* w     = (const float*)d_in[14];

    char* ws = (char*)d_ws;
    f16* qx4   = (f16*)(ws + 0);
    f16* kx4   = (f16*)(ws + 8388608);
    f16* vT    = (f16*)(ws + 16777216);
    f16* WFt   = (f16*)(ws + 25165824);
    f16* Qh    = (f16*)(ws + 27262976);
    f16* Kh    = (f16*)(ws + 35651584);
    f16* Vh    = (f16*)(ws + 44040192);
    f16* WQt   = (f16*)(ws + 52428800);
    f16* WKt   = (f16*)(ws + 54525952);
    f16* WVt   = (f16*)(ws + 56623104);
    f16* CTq   = (f16*)(ws + 58720256);
    f16* XtQ   = (f16*)(ws + 27262976);  // over dead Qh (+Kh head)
    f16* XtK   = (f16*)(ws + 35676160);  // over dead Kh (+Vh head)
    f16* CTk   = (f16*)(ws + 44089344);  // over dead Vh (+WQt head) - AFTER proj!
    float* Opart = (float*)(ws + 27262976);  // 32MB over dead Xt/CTk
    float* Lpart = (float*)(ws + 60817408);  // 0.5MB (ends 61.34M < 64MiB)
    f16* ctxb  = (f16*)(ws + 0);             // over dead qx4

    dim3 b256(256), bT(32, 8);

    // 1) fp32 -> fp16 inputs (one launch)
    k_cvt_all<<<12288, b256, 0, stream>>>(Q, K, V, Qh, Kh, Vh);
    // 2) weight transposes for projections
    k_wtrans<<<dim3(32, 32, 4), bT, 0, stream>>>(WQ, WK, WV, Wfc,
                                                 WQt, WKt, WVt, WFt);
    // 3) projections -> qx4, kx4, vT
    k_gemm_proj<<<dim3(8, 32, 3), b256, 0, stream>>>(Qh, Kh, Vh, WQt, WKt, WVt,
                                                     bQ, bK, bV, qx4, kx4, vT);
    // 4) conv A-operand: transpose + zero-pad (over dead Qh/Kh/Vh)
    k_transpose_pad<<<dim3(32, 33, 8), bT, 0, stream>>>(qx4, kx4, XtQ, XtK);
    // 5) conv weight transposes (CTk over dead Vh/WQt -- must be after proj)
    k_ctrans<<<dim3(128, 32, 2), bT, 0, stream>>>(convq, convk, CTq, CTk);
    // 6) fused conv GEMM + residual in place (both tensors)
    k_gemm_conv<<<dim3(8, 8, 8), b256, 0, stream>>>(XtQ, XtK, CTq, CTk,
                                                    qx4, kx4, w);
    // 7) flash attention partials (KV split x2)
    k_attn<<<dim3(64, 8, 2), b256, 0, stream>>>(qx4, kx4, vT, Opart, Lpart);
    // 8) combine partials -> ctx (over dead qx4)
    k_combine<<<4096, b256, 0, stream>>>(Opart, Lpart, ctxb);
    // 9) final projection -> f32 output
    k_gemm_final<<<dim3(8, 32), b256, 0, stream>>>(ctxb, WFt, bfc, (float*)d_out);
}

// Round 12
// 182.189 us; speedup vs baseline: 1.6925x; 1.3674x over previous
//
#include <hip/hip_runtime.h>
#include <hip/hip_bf16.h>

typedef _Float16 f16;
typedef _Float16 f16x2 __attribute__((ext_vector_type(2)));
typedef _Float16 f16x4 __attribute__((ext_vector_type(4)));
typedef _Float16 f16x8 __attribute__((ext_vector_type(8)));
typedef float f32x4 __attribute__((ext_vector_type(4)));

// cvt_pkrtz returns __fp16 ext_vector(2); re-cast to our f16x2 (same bits).
__device__ __forceinline__ f16x2 pkrtz(float a, float b) {
    auto r = __builtin_amdgcn_cvt_pkrtz(a, b);
    f16x2 o; o[0] = (f16)r[0]; o[1] = (f16)r[1];
    return o;
}

#define XT_ROWS 1027
#define XT_BSTRIDE (XT_ROWS * 1024)   // elems per batch

// ---------------------------------------------------------------------------
// global -> LDS direct (16B per lane, wave-uniform LDS base + lane*16)
// ---------------------------------------------------------------------------
__device__ __forceinline__ void gload16(const f16* g, f16* l) {
    __builtin_amdgcn_global_load_lds(
        (const __attribute__((address_space(1))) void*)g,
        (__attribute__((address_space(3))) void*)l, 16, 0, 0);
}

// ---------------------------------------------------------------------------
// Stage a 128x64 f16 tile from row-major src (ld elems) into 16KB LDS.
// XOR-swizzle on the SOURCE col, same XOR on the read side (involution).
// ---------------------------------------------------------------------------
__device__ __forceinline__ void stage_tile(const f16* src, int ld, f16* lds)
{
    const int tid = threadIdx.x;
    const int w512 = (tid >> 6) << 9;          // wave base (f16 elems)
    #pragma unroll
    for (int q = 0; q < 4; ++q) {
        const int s = q * 256 + tid;           // 16B slot id, 0..1023
        const int row = s >> 3;
        const int col = ((s & 7) ^ (row & 7)) << 3;
        gload16(src + row * ld + col, lds + (q << 11) + w512);
    }
}

// ---------------------------------------------------------------------------
// Stage a 64x64 f16 tile (8KB) the same way (512 slots, 2 per thread).
// ---------------------------------------------------------------------------
__device__ __forceinline__ void stage64(const f16* src, int ld, f16* lds)
{
    const int tid = threadIdx.x;
    const int w512 = (tid >> 6) << 9;
    #pragma unroll
    for (int q = 0; q < 2; ++q) {
        const int s = q * 256 + tid;           // 16B slot id, 0..511
        const int row = s >> 3;
        const int col = ((s & 7) ^ (row & 7)) << 3;
        gload16(src + row * ld + col, lds + (q << 11) + w512);
    }
}

// ---------------------------------------------------------------------------
// GEMM core, reg-prefetch pipelined: C(128x128) += A(128xK) * Bt(128xK)^T.
// CONV=1: A row base = m0 + (k0>>10) into zero-padded Xt, col = k0&1023.
// ---------------------------------------------------------------------------
template <int CONV>
__device__ __forceinline__ void gemm_core64(
    const f16* __restrict__ A, int lda, int m0,
    const f16* __restrict__ Bt, int ldb, int K,
    f16* Alds, f16* Blds, f32x4 acc[4][4])
{
    const int tid = threadIdx.x;
    const int lid = tid & 63;
    const int wv  = tid >> 6;
    const int wm  = (wv >> 1) * 64;
    const int wn  = (wv & 1) * 64;
    const int g   = lid >> 4;
    const int r15 = lid & 15;

    stage_tile(A + m0 * lda, lda, Alds);
    stage_tile(Bt, ldb, Blds);
    asm volatile("s_waitcnt vmcnt(0)" ::: "memory");
    __builtin_amdgcn_s_barrier();

    for (int k0 = 0; k0 < K; k0 += 64) {
        f16x8 af[2][4], bf[2][4];
        #pragma unroll
        for (int kc = 0; kc < 2; ++kc) {
            #pragma unroll
            for (int mi = 0; mi < 4; ++mi) {
                const int row = wm + mi * 16 + r15;
                af[kc][mi] = *(const f16x8*)(Alds + row * 64 +
                                             (((kc * 4 + g) ^ (row & 7)) << 3));
            }
            #pragma unroll
            for (int nj = 0; nj < 4; ++nj) {
                const int row = wn + nj * 16 + r15;
                bf[kc][nj] = *(const f16x8*)(Blds + row * 64 +
                                             (((kc * 4 + g) ^ (row & 7)) << 3));
            }
        }
        asm volatile("s_waitcnt lgkmcnt(0)" ::: "memory");
        __builtin_amdgcn_sched_barrier(0);
        __builtin_amdgcn_s_barrier();
        const int k1 = k0 + 64;
        if (k1 < K) {
            const f16* Asrc;
            if (CONV) Asrc = A + (m0 + (k1 >> 10)) * lda + (k1 & 1023);
            else      Asrc = A + m0 * lda + k1;
            stage_tile(Asrc, lda, Alds);
            stage_tile(Bt + k1, ldb, Blds);
        }
        __builtin_amdgcn_sched_barrier(0);
        #pragma unroll
        for (int kc = 0; kc < 2; ++kc)
            #pragma unroll
            for (int mi = 0; mi < 4; ++mi)
                #pragma unroll
                for (int nj = 0; nj < 4; ++nj)
                    acc[mi][nj] = __builtin_amdgcn_mfma_f32_16x16x32_f16(
                        af[kc][mi], bf[kc][nj], acc[mi][nj], 0, 0, 0);
        __builtin_amdgcn_sched_barrier(0);
        asm volatile("s_waitcnt vmcnt(0)" ::: "memory");
        __builtin_amdgcn_s_barrier();
    }
}

// ---------------------------------------------------------------------------
// Fused fp32 -> fp16 convert for Q,K,V (grid 3*4096 blocks).
// ---------------------------------------------------------------------------
__global__ __launch_bounds__(256) void k_cvt_all(
    const float* __restrict__ Q, const float* __restrict__ K,
    const float* __restrict__ V, f16* __restrict__ Qh,
    f16* __restrict__ Kh, f16* __restrict__ Vh)
{
    const int bid = blockIdx.x;
    const int which = bid >> 12;
    const int i = (bid & 4095) * 256 + threadIdx.x;
    const float* in = which == 0 ? Q : which == 1 ? K : V;
    f16* out = which == 0 ? Qh : which == 1 ? Kh : Vh;
    float4 v = ((const float4*)in)[i];
    f16x4 o;
    o[0] = (f16)v.x; o[1] = (f16)v.y; o[2] = (f16)v.z; o[3] = (f16)v.w;
    ((f16x4*)out)[i] = o;
}

// ---------------------------------------------------------------------------
// Fused transpose+convert for the 4 1024x1024 weights.  grid (32,32,4).
// ---------------------------------------------------------------------------
__global__ __launch_bounds__(256) void k_wtrans(
    const float* __restrict__ WQ, const float* __restrict__ WK,
    const float* __restrict__ WV, const float* __restrict__ Wfc,
    f16* __restrict__ WQt, f16* __restrict__ WKt,
    f16* __restrict__ WVt, f16* __restrict__ WFt)
{
    const int z = blockIdx.z;
    const float* in = z == 0 ? WQ : z == 1 ? WK : z == 2 ? WV : Wfc;
    f16* out = z == 0 ? WQt : z == 1 ? WKt : z == 2 ? WVt : WFt;
    __shared__ float tile[32][33];
    int c0 = blockIdx.x * 32, r0 = blockIdx.y * 32;
    int tx = threadIdx.x, ty = threadIdx.y;
    #pragma unroll
    for (int i = ty; i < 32; i += 8)
        tile[i][tx] = in[(size_t)(r0 + i) * 1024 + c0 + tx];
    __syncthreads();
    #pragma unroll
    for (int i = ty; i < 32; i += 8)
        out[(size_t)(c0 + i) * 1024 + r0 + tx] = (f16)tile[tx][i];
}

// ---------------------------------------------------------------------------
// Fused transpose+convert for conv weights (1024 x 4096).  grid (128,32,2).
// NOTE: must launch AFTER projections — CTk overlays dead Vh/WQt.
// ---------------------------------------------------------------------------
__global__ __launch_bounds__(256) void k_ctrans(
    const float* __restrict__ convq, const float* __restrict__ convk,
    f16* __restrict__ CTq, f16* __restrict__ CTk)
{
    const float* in = blockIdx.z ? convk : convq;
    f16* out = blockIdx.z ? CTk : CTq;
    __shared__ float tile[32][33];
    int c0 = blockIdx.x * 32, r0 = blockIdx.y * 32;
    int tx = threadIdx.x, ty = threadIdx.y;
    #pragma unroll
    for (int i = ty; i < 32; i += 8)
        tile[i][tx] = in[(size_t)(r0 + i) * 4096 + c0 + tx];
    __syncthreads();
    #pragma unroll
    for (int i = ty; i < 32; i += 8)
        out[(size_t)(c0 + i) * 1024 + r0 + tx] = (f16)tile[tx][i];
}

// ---------------------------------------------------------------------------
// Transpose + zero-pad for the conv A-operand.  grid (32,33,8).
// ---------------------------------------------------------------------------
__global__ __launch_bounds__(256) void k_transpose_pad(
    const f16* __restrict__ qx4, const f16* __restrict__ kx4,
    f16* __restrict__ XtQ, f16* __restrict__ XtK)
{
    int z = blockIdx.z, b = z & 3, ten = z >> 2;
    const f16* in = (ten ? kx4 : qx4) + (size_t)b * 1048576;
    f16* out = (ten ? XtK : XtQ) + (size_t)b * XT_BSTRIDE;
    __shared__ f16 tile[32][33];
    int c0 = blockIdx.x * 32;
    int tp0 = blockIdx.y * 32;
    int tx = threadIdx.x, ty = threadIdx.y;
    #pragma unroll
    for (int i = ty; i < 32; i += 8) {
        int t = tp0 + tx - 2;
        tile[i][tx] = (t >= 0 && t < 1024) ? in[(c0 + i) * 1024 + t] : (f16)0.f;
    }
    __syncthreads();
    #pragma unroll
    for (int i = ty; i < 32; i += 8) {
        int tp = tp0 + i;
        if (tp < XT_ROWS) out[tp * 1024 + c0 + tx] = tile[tx][i];
    }
}

// ---------------------------------------------------------------------------
// Projection GEMMs: z=0: q -> qx4 ; z=1: k -> kx4 ; z=2: v -> vT
// ---------------------------------------------------------------------------
__global__ __launch_bounds__(256) void k_gemm_proj(
    const f16* __restrict__ Qh, const f16* __restrict__ Kh, const f16* __restrict__ Vh,
    const f16* __restrict__ WQt, const f16* __restrict__ WKt, const f16* __restrict__ WVt,
    const float* __restrict__ bQ, const float* __restrict__ bK, const float* __restrict__ bV,
    f16* __restrict__ qx4, f16* __restrict__ kx4, f16* __restrict__ vT)
{
    __shared__ __align__(16) f16 Alds[128 * 64];
    __shared__ __align__(16) f16 Blds[128 * 64];
    const int z = blockIdx.z;
    const f16* A  = z == 0 ? Qh : z == 1 ? Kh : Vh;
    const f16* Bt = z == 0 ? WQt : z == 1 ? WKt : WVt;
    const float* bias = z == 0 ? bQ : z == 1 ? bK : bV;
    f16* dst = z == 0 ? qx4 : z == 1 ? kx4 : vT;
    const int m0 = blockIdx.y * 128, n0 = blockIdx.x * 128;
    f32x4 acc[4][4] = {};
    gemm_core64<0>(A, 1024, m0, Bt + n0 * 1024, 1024, 1024, Alds, Blds, acc);

    const int tid = threadIdx.x, lid = tid & 63, wv = tid >> 6;
    const int wm = (wv >> 1) * 64, wn = (wv & 1) * 64, g = lid >> 4, r15 = lid & 15;
    #pragma unroll
    for (int nj = 0; nj < 4; ++nj) {
        const int col = n0 + wn + nj * 16 + r15;
        const float bv = bias[col];
        const int h = col >> 6, d = col & 63;
        #pragma unroll
        for (int mi = 0; mi < 4; ++mi)
            #pragma unroll
            for (int j = 0; j < 4; ++j) {
                const int row = m0 + wm + mi * 16 + g * 4 + j;
                const int b = row >> 10, l = row & 1023;
                const float v = acc[mi][nj][j] + bv;
                const int off = b * 1048576 + h * 65536 +
                                (z == 2 ? (d * 1024 + l) : (l * 64 + d));
                dst[off] = (f16)v;
            }
    }
}

// ---------------------------------------------------------------------------
// Fused conv GEMM + residual IN PLACE.  grid (8, 8, 8): z = ten*4+b.
// ---------------------------------------------------------------------------
__global__ __launch_bounds__(256) void k_gemm_conv(
    const f16* __restrict__ XtQ, const f16* __restrict__ XtK,
    const f16* __restrict__ CTq, const f16* __restrict__ CTk,
    f16* __restrict__ qx4, f16* __restrict__ kx4,
    const float* __restrict__ wvec)
{
    __shared__ __align__(16) f16 Alds[128 * 64];
    __shared__ __align__(16) f16 Blds[128 * 64];
    const int z = blockIdx.z, b = z & 3, ten = z >> 2;
    const f16* Xt = (ten ? XtK : XtQ) + (size_t)b * XT_BSTRIDE;
    const f16* CT = ten ? CTk : CTq;
    f16* dst = (ten ? kx4 : qx4) + (size_t)b * 1048576;

    const int flen = (2.f * wvec[0] >= 4.f * wvec[1]) ? 2 : 4;
    const int K = flen << 10;

    const int m0 = blockIdx.y * 128, n0 = blockIdx.x * 128;
    f32x4 acc[4][4] = {};
    gemm_core64<1>(Xt, 1024, m0, CT + n0 * 4096, 4096, K, Alds, Blds, acc);

    const int tid = threadIdx.x, lid = tid & 63, wv = tid >> 6;
    const int wm = (wv >> 1) * 64, wn = (wv & 1) * 64, g = lid >> 4, r15 = lid & 15;
    #pragma unroll
    for (int nj = 0; nj < 4; ++nj) {
        const int col = n0 + wn + nj * 16 + r15;
        #pragma unroll
        for (int mi = 0; mi < 4; ++mi)
            #pragma unroll
            for (int j = 0; j < 4; ++j) {
                const int row = m0 + wm + mi * 16 + g * 4 + j;
                const int i = row * 1024 + col;
                dst[i] = (f16)(acc[mi][nj][j] + (float)dst[i]);
            }
    }
}

// ---------------------------------------------------------------------------
// Flash attention with LDS-staged K/V tiles (coalesced, shared by all 4
// waves) + double-buffered raw-barrier pipeline.  grid (64 bh, 8 qt).
// Swapped QK^T; constant-shift exp; deferred row-sum; sigma' k-slot
// bijection on both PV operands.  LDS: 2 x (8KB K + 8KB V), XOR-swizzled.
// ---------------------------------------------------------------------------
__device__ __forceinline__ void attn_tile(
    const f16* KL, const f16* VL,
    const f16* Kn, const f16* Vn, f16* KLn, f16* VLn, bool doStage,
    const f16x8 qf[2][2], f32x4 o[2][4], f32x4 lsum[2], int g, int r15)
{
    // --- ds_read K fragments (swizzled b128)
    f16x8 kf[4][2];
    #pragma unroll
    for (int nj = 0; nj < 4; ++nj)
        #pragma unroll
        for (int kc = 0; kc < 2; ++kc) {
            const int row = nj * 16 + r15;
            kf[nj][kc] = *(const f16x8*)(KL + row * 64 +
                                         (((kc * 4 + g) ^ (row & 7)) << 3));
        }
    // --- ds_read V fragments (two swizzled b64 per fragment)
    f16x4 vlo[4][2], vhi[4][2];
    #pragma unroll
    for (int db = 0; db < 4; ++db)
        #pragma unroll
        for (int ch = 0; ch < 2; ++ch) {
            const int row = db * 16 + r15;
            const int c1 = ch * 4 + (g >> 1);
            const int c2 = c1 + 2;
            const int sub = (g & 1) * 4;
            vlo[db][ch] = *(const f16x4*)(VL + row * 64 +
                                          ((c1 ^ (row & 7)) << 3) + sub);
            vhi[db][ch] = *(const f16x4*)(VL + row * 64 +
                                          ((c2 ^ (row & 7)) << 3) + sub);
        }
    asm volatile("s_waitcnt lgkmcnt(0)" ::: "memory");
    __builtin_amdgcn_sched_barrier(0);
    __builtin_amdgcn_s_barrier();          // all waves done reading this buf
    // --- issue next tile's staging (flies under compute)
    if (doStage) {
        stage64(Kn, 64, KLn);
        stage64(Vn, 1024, VLn);
    }
    __builtin_amdgcn_sched_barrier(0);
    // --- QK^T (swapped): col=q=r15, row=k=g*4+j (+nj*16)
    f32x4 sacc[2][4] = {};
    #pragma unroll
    for (int nj = 0; nj < 4; ++nj)
        #pragma unroll
        for (int kc = 0; kc < 2; ++kc) {
            sacc[0][nj] = __builtin_amdgcn_mfma_f32_16x16x32_f16(
                kf[nj][kc], qf[0][kc], sacc[0][nj], 0, 0, 0);
            sacc[1][nj] = __builtin_amdgcn_mfma_f32_16x16x32_f16(
                kf[nj][kc], qf[1][kc], sacc[1][nj], 0, 0, 0);
        }
    // --- exp(s-2), row-sum partials, pack, PV
    #pragma unroll
    for (int qh = 0; qh < 2; ++qh) {
        f32x4 pe[4];
        #pragma unroll
        for (int nj = 0; nj < 4; ++nj) {
            #pragma unroll
            for (int j = 0; j < 4; ++j)
                pe[nj][j] = __expf(sacc[qh][nj][j] - 2.0f);
            lsum[qh] += pe[nj];
        }
        f16x8 pb[2];
        #pragma unroll
        for (int ch = 0; ch < 2; ++ch) {
            union { f16x2 h2[4]; f16x8 v8; } u;
            u.h2[0] = pkrtz(pe[2 * ch][0], pe[2 * ch][1]);
            u.h2[1] = pkrtz(pe[2 * ch][2], pe[2 * ch][3]);
            u.h2[2] = pkrtz(pe[2 * ch + 1][0], pe[2 * ch + 1][1]);
            u.h2[3] = pkrtz(pe[2 * ch + 1][2], pe[2 * ch + 1][3]);
            pb[ch] = u.v8;
        }
        #pragma unroll
        for (int db = 0; db < 4; ++db)
            #pragma unroll
            for (int ch = 0; ch < 2; ++ch) {
                union { f16x4 h4[2]; f16x8 v8; } w;
                w.h4[0] = vlo[db][ch];
                w.h4[1] = vhi[db][ch];
                o[qh][db] = __builtin_amdgcn_mfma_f32_16x16x32_f16(
                    w.v8, pb[ch], o[qh][db], 0, 0, 0);
            }
    }
    __builtin_amdgcn_sched_barrier(0);
    asm volatile("s_waitcnt vmcnt(0)" ::: "memory");
    __builtin_amdgcn_s_barrier();          // staged data landed
}

__global__ __launch_bounds__(256) void k_attn(
    const f16* __restrict__ qn, const f16* __restrict__ kn,
    const f16* __restrict__ vT, f16* __restrict__ ctx)
{
    __shared__ __align__(16) f16 lds[4][4096];   // K0 V0 K1 V1
    const int bh = blockIdx.x, b = bh >> 4, h = bh & 15;
    const f16* Qp = qn + (size_t)b * 1048576 + h * 65536;
    const f16* Kp = kn + (size_t)b * 1048576 + h * 65536;
    const f16* Vp = vT + (size_t)b * 1048576 + h * 65536;
    const int tid = threadIdx.x, lid = tid & 63, wv = tid >> 6;
    const int g = lid >> 4, r15 = lid & 15;
    const int q0 = blockIdx.y * 128 + wv * 32;

    // Q B-fragments, pre-scaled by 1/8 (exact)
    f16x8 qf[2][2];
    #pragma unroll
    for (int qh = 0; qh < 2; ++qh)
        #pragma unroll
        for (int kc = 0; kc < 2; ++kc) {
            f16x8 t = *(const f16x8*)(Qp + (q0 + qh * 16 + r15) * 64 + kc * 32 + g * 8);
            #pragma unroll
            for (int e = 0; e < 8; ++e) t[e] = t[e] * (f16)0.125f;
            qf[qh][kc] = t;
        }

    f32x4 o[2][4] = {};
    f32x4 lsum[2] = {};

    // prologue: stage tile 0
    stage64(Kp, 64, lds[0]);
    stage64(Vp, 1024, lds[1]);
    asm volatile("s_waitcnt vmcnt(0)" ::: "memory");
    __builtin_amdgcn_s_barrier();

    for (int tt = 0; tt < 8; ++tt) {
        const int t1 = 2 * tt + 1;
        attn_tile(lds[0], lds[1], Kp + t1 * 4096, Vp + t1 * 64,
                  lds[2], lds[3], true, qf, o, lsum, g, r15);
        attn_tile(lds[2], lds[3], Kp + (t1 + 1) * 4096, Vp + (t1 + 1) * 64,
                  lds[0], lds[1], tt < 7, qf, o, lsum, g, r15);
    }

    // Row sums: in-lane horizontal + reduce over g-groups (xor 16,32)
    float inv[2];
    #pragma unroll
    for (int qh = 0; qh < 2; ++qh) {
        float lr = lsum[qh][0] + lsum[qh][1] + lsum[qh][2] + lsum[qh][3];
        lr += __shfl_xor(lr, 16);
        lr += __shfl_xor(lr, 32);
        inv[qh] = 1.0f / lr;
    }
    // Normalize + transpose via per-wave slice of the (now free) staging LDS.
    f16* Olds = &lds[0][0] + wv * (32 * 72);
    #pragma unroll
    for (int qh = 0; qh < 2; ++qh)
        #pragma unroll
        for (int db = 0; db < 4; ++db) {
            const int row = qh * 16 + r15, col = db * 16 + g * 4;
            *(f16x2*)(Olds + row * 72 + col) =
                pkrtz(o[qh][db][0] * inv[qh], o[qh][db][1] * inv[qh]);
            *(f16x2*)(Olds + row * 72 + col + 2) =
                pkrtz(o[qh][db][2] * inv[qh], o[qh][db][3] * inv[qh]);
        }
    asm volatile("s_waitcnt lgkmcnt(0)" ::: "memory");
    __builtin_amdgcn_sched_barrier(0);
    #pragma unroll
    for (int p = 0; p < 4; ++p) {
        const int row = p * 8 + (lid >> 3);
        const int c8 = (lid & 7) * 8;
        f16x8 v = *(const f16x8*)(Olds + row * 72 + c8);
        *(f16x8*)(ctx + (size_t)b * 1048576 + (q0 + row) * 1024 + h * 64 + c8) = v;
    }
}

// ---------------------------------------------------------------------------
// Final GEMM: out = ctx @ Wfc + bfc, output FLOAT32 (B,L,1024) row-major.
// ---------------------------------------------------------------------------
__global__ __launch_bounds__(256) void k_gemm_final(
    const f16* __restrict__ ctx, const f16* __restrict__ WFt,
    const float* __restrict__ bfc, float* __restrict__ out)
{
    __shared__ __align__(16) f16 Alds[128 * 64];
    __shared__ __align__(16) f16 Blds[128 * 64];
    const int m0 = blockIdx.y * 128, n0 = blockIdx.x * 128;
    f32x4 acc[4][4] = {};
    gemm_core64<0>(ctx, 1024, m0, WFt + n0 * 1024, 1024, 1024, Alds, Blds, acc);

    const int tid = threadIdx.x, lid = tid & 63, wv = tid >> 6;
    const int wm = (wv >> 1) * 64, wn = (wv & 1) * 64, g = lid >> 4, r15 = lid & 15;
    #pragma unroll
    for (int nj = 0; nj < 4; ++nj) {
        const int col = n0 + wn + nj * 16 + r15;
        const float bv = bfc[col];
        #pragma unroll
        for (int mi = 0; mi < 4; ++mi)
            #pragma unroll
            for (int j = 0; j < 4; ++j) {
                const int row = m0 + wm + mi * 16 + g * 4 + j;
                out[(size_t)row * 1024 + col] = acc[mi][nj][j] + bv;
            }
    }
}

// ---------------------------------------------------------------------------
// Workspace (64 MiB), byte-exact offsets; lifetime schedule:
//   qx4 @0  kx4 @8M  vT @16M  WFt @24M (live: proj..final)
//   Qh @26M  Kh @34M  Vh @42M  WQt @50M  WKt @52M  WVt @54M  CTq @56M
//   After proj: XtQ @26M  XtK @34.03M  CTk @42.05M (over dead Vh/WQt)
//   After conv: ctxb @26M over dead XtQ (attn -> final)
//   ORDER: k_ctrans AFTER k_gemm_proj (CTk overlays Vh/WQt).
// ---------------------------------------------------------------------------
extern "C" void kernel_launch(void* const* d_in, const int* in_sizes, int n_in,
                              void* d_out, int out_size, void* d_ws, size_t ws_size,
                              hipStream_t stream)
{
    (void)in_sizes; (void)n_in; (void)out_size; (void)ws_size;
    const float* Q     = (const float*)d_in[0];
    const float* K     = (const float*)d_in[1];
    const float* V     = (const float*)d_in[2];
    // d_in[3] = attn_mask (unused by reference)
    const float* WQ    = (const float*)d_in[4];
    const float* bQ    = (const float*)d_in[5];
    const float* WK    = (const float*)d_in[6];
    const float* bK    = (const float*)d_in[7];
    const float* WV    = (const float*)d_in[8];
    const float* bV    = (const float*)d_in[9];
    const float* Wfc   = (const float*)d_in[10];
    const float* bfc   = (const float*)d_in[11];
    const float* convq = (const float*)d_in[12];
    const float* convk = (const float*)d_in[13];
    const float* w     = (const float*)d_in[14];

    char* ws = (char*)d_ws;
    f16* qx4   = (f16*)(ws + 0);
    f16* kx4   = (f16*)(ws + 8388608);
    f16* vT    = (f16*)(ws + 16777216);
    f16* WFt   = (f16*)(ws + 25165824);
    f16* Qh    = (f16*)(ws + 27262976);
    f16* Kh    = (f16*)(ws + 35651584);
    f16* Vh    = (f16*)(ws + 44040192);
    f16* WQt   = (f16*)(ws + 52428800);
    f16* WKt   = (f16*)(ws + 54525952);
    f16* WVt   = (f16*)(ws + 56623104);
    f16* CTq   = (f16*)(ws + 58720256);
    f16* XtQ   = (f16*)(ws + 27262976);  // over dead Qh (+Kh head)
    f16* XtK   = (f16*)(ws + 35676160);  // over dead Kh (+Vh head)
    f16* CTk   = (f16*)(ws + 44089344);  // over dead Vh (+WQt head) - AFTER proj!
    f16* ctxb  = (f16*)(ws + 27262976);  // over dead XtQ (attn->final)

    dim3 b256(256), bT(32, 8);

    // 1) fp32 -> fp16 inputs
    k_cvt_all<<<12288, b256, 0, stream>>>(Q, K, V, Qh, Kh, Vh);
    // 2) weight transposes for projections
    k_wtrans<<<dim3(32, 32, 4), bT, 0, stream>>>(WQ, WK, WV, Wfc,
                                                 WQt, WKt, WVt, WFt);
    // 3) projections -> qx4, kx4, vT
    k_gemm_proj<<<dim3(8, 32, 3), b256, 0, stream>>>(Qh, Kh, Vh, WQt, WKt, WVt,
                                                     bQ, bK, bV, qx4, kx4, vT);
    // 4) conv A-operand: transpose + zero-pad (over dead Qh/Kh/Vh)
    k_transpose_pad<<<dim3(32, 33, 8), bT, 0, stream>>>(qx4, kx4, XtQ, XtK);
    // 5) conv weight transposes (CTk over dead Vh/WQt -- must be after proj)
    k_ctrans<<<dim3(128, 32, 2), bT, 0, stream>>>(convq, convk, CTq, CTk);
    // 6) fused conv GEMM + residual in place
    k_gemm_conv<<<dim3(8, 8, 8), b256, 0, stream>>>(XtQ, XtK, CTq, CTk,
                                                    qx4, kx4, w);
    // 7) flash attention -> ctx (LDS-staged K/V; XCD-friendly grid x=bh)
    k_attn<<<dim3(64, 8), b256, 0, stream>>>(qx4, kx4, vT, ctxb);
    // 8) final projection -> f32 output
    k_gemm_final<<<dim3(8, 32), b256, 0, stream>>>(ctxb, WFt, bfc, (float*)d_out);
}